// Round 1
// baseline (1838.486 us; speedup 1.0000x reference)
//
#include <hip/hip_runtime.h>
#include <cfloat>
#include <cmath>

#define NN 10000
#define EE 160000
#define ETOT 170000   // EE + NN self loops

// ---------------------------------------------------------------- CSR build
__global__ __launch_bounds__(256) void count_deg_k(const int* __restrict__ ei,
                                                   int* __restrict__ deg) {
    int e = blockIdx.x * 256 + threadIdx.x;
    if (e < ETOT) {
        int dst = (e < EE) ? ei[EE + e] : (e - EE);
        atomicAdd(&deg[dst], 1);
    }
}

__global__ __launch_bounds__(1024) void scan_k(const int* __restrict__ deg,
                                               int* __restrict__ offs,
                                               int* __restrict__ pos) {
    __shared__ int s[1024];
    __shared__ int carry_sh;
    const int tid = threadIdx.x;
    if (tid == 0) carry_sh = 0;
    __syncthreads();
    for (int base = 0; base < NN; base += 1024) {
        int i = base + tid;
        int v = (i < NN) ? deg[i] : 0;
        s[tid] = v;
        __syncthreads();
        for (int d = 1; d < 1024; d <<= 1) {
            int t = (tid >= d) ? s[tid - d] : 0;
            __syncthreads();
            s[tid] += t;
            __syncthreads();
        }
        int total = s[1023];
        int carry = carry_sh;
        if (i < NN) {
            offs[i + 1] = carry + s[tid];
            pos[i]      = carry + s[tid] - v;   // exclusive scan
        }
        __syncthreads();
        if (tid == 0) carry_sh = carry + total;
        __syncthreads();
    }
    if (tid == 0) offs[0] = 0;
}

__global__ __launch_bounds__(256) void scatter_k(const int* __restrict__ ei,
                                                 int* __restrict__ pos,
                                                 int* __restrict__ ebuf) {
    int e = blockIdx.x * 256 + threadIdx.x;
    if (e < ETOT) {
        int dst = (e < EE) ? ei[EE + e] : (e - EE);
        int p = atomicAdd(&pos[dst], 1);
        ebuf[p] = e;
    }
}

// ---------------------------------------------------------------- GEMM fp32
// C[M,Nc] = A[M,K] @ B[K,Nc] (+ bias1 + bias2). 128x128 tile, 8x8 microtile.
#define BM 128
#define BN 128
#define BK 16

template <bool BIAS>
__global__ __launch_bounds__(256) void gemm_k(const float* __restrict__ A,
                                              const float* __restrict__ B,
                                              float* __restrict__ C,
                                              const float* __restrict__ bias1,
                                              const float* __restrict__ bias2,
                                              int M, int K, int Nc) {
    __shared__ float As[BK][BM + 4];   // pad keeps float4 alignment, spreads banks
    __shared__ float Bs[BK][BN];
    const int tid = threadIdx.x;
    const int tx = tid & 15;           // 0..15  -> col block
    const int ty = tid >> 4;           // 0..15  -> row block
    const int m0 = blockIdx.y * BM;
    const int n0 = blockIdx.x * BN;

    const int aRow = tid >> 1;         // 0..127
    const int aK   = (tid & 1) * 8;    // 0 or 8
    const int bRow = tid >> 4;         // 0..15
    const int bCol = (tid & 15) * 8;   // 0..120

    float acc[8][8];
#pragma unroll
    for (int i = 0; i < 8; i++)
#pragma unroll
        for (int j = 0; j < 8; j++) acc[i][j] = 0.f;

    for (int k0 = 0; k0 < K; k0 += BK) {
        const int ar = m0 + aRow;
        float4 a0, a1;
        if (ar < M) {
            const float* ap = A + (size_t)ar * K + k0 + aK;
            a0 = *reinterpret_cast<const float4*>(ap);
            a1 = *reinterpret_cast<const float4*>(ap + 4);
        } else {
            a0 = make_float4(0.f, 0.f, 0.f, 0.f);
            a1 = a0;
        }
        As[aK + 0][aRow] = a0.x; As[aK + 1][aRow] = a0.y;
        As[aK + 2][aRow] = a0.z; As[aK + 3][aRow] = a0.w;
        As[aK + 4][aRow] = a1.x; As[aK + 5][aRow] = a1.y;
        As[aK + 6][aRow] = a1.z; As[aK + 7][aRow] = a1.w;

        const float* bp = B + (size_t)(k0 + bRow) * Nc + n0 + bCol;
        *reinterpret_cast<float4*>(&Bs[bRow][bCol])     = *reinterpret_cast<const float4*>(bp);
        *reinterpret_cast<float4*>(&Bs[bRow][bCol + 4]) = *reinterpret_cast<const float4*>(bp + 4);
        __syncthreads();

#pragma unroll
        for (int k = 0; k < BK; k++) {
            float4 av0 = *reinterpret_cast<const float4*>(&As[k][ty * 8]);
            float4 av1 = *reinterpret_cast<const float4*>(&As[k][ty * 8 + 4]);
            float4 bv0 = *reinterpret_cast<const float4*>(&Bs[k][tx * 8]);
            float4 bv1 = *reinterpret_cast<const float4*>(&Bs[k][tx * 8 + 4]);
            const float a[8] = {av0.x, av0.y, av0.z, av0.w, av1.x, av1.y, av1.z, av1.w};
            const float b[8] = {bv0.x, bv0.y, bv0.z, bv0.w, bv1.x, bv1.y, bv1.z, bv1.w};
#pragma unroll
            for (int i = 0; i < 8; i++)
#pragma unroll
                for (int j = 0; j < 8; j++) acc[i][j] += a[i] * b[j];
        }
        __syncthreads();
    }

#pragma unroll
    for (int i = 0; i < 8; i++) {
        int row = m0 + ty * 8 + i;
        if (row < M) {
            float* cp = C + (size_t)row * Nc + n0 + tx * 8;
#pragma unroll
            for (int j = 0; j < 8; j++) {
                float v = acc[i][j];
                if (BIAS) {
                    int col = n0 + tx * 8 + j;
                    v += bias1[col] + bias2[col];
                }
                cp[j] = v;
            }
        }
    }
}

// ------------------------------------------------------- attention logits
// al_s[n,h] = dot(hfeat[n,h,:], a_s[h,:]);  al_d likewise. one wave per (n,h)
__global__ __launch_bounds__(256) void att_k(const float* __restrict__ hfeat,
                                             const float* __restrict__ a_s,
                                             const float* __restrict__ a_d,
                                             float* __restrict__ al_s,
                                             float* __restrict__ al_d,
                                             int H, int HC) {
    int idx = blockIdx.x * 4 + (threadIdx.x >> 6);
    if (idx >= NN * H) return;
    int lane = threadIdx.x & 63;
    int n = idx / H, h = idx - n * H;
    const float4 hv = *reinterpret_cast<const float4*>(hfeat + (size_t)n * HC + h * 256 + lane * 4);
    const float4 sv = *reinterpret_cast<const float4*>(a_s + h * 256 + lane * 4);
    const float4 dv = *reinterpret_cast<const float4*>(a_d + h * 256 + lane * 4);
    float ss = hv.x * sv.x + hv.y * sv.y + hv.z * sv.z + hv.w * sv.w;
    float sd = hv.x * dv.x + hv.y * dv.y + hv.z * dv.z + hv.w * dv.w;
    for (int o = 32; o > 0; o >>= 1) {
        ss += __shfl_xor(ss, o, 64);
        sd += __shfl_xor(sd, o, 64);
    }
    if (lane == 0) { al_s[idx] = ss; al_d[idx] = sd; }
}

// --------------------------------------------------------------- softmax
// one wave per (n,h): max over incoming edges, exp, sum, normalize
__global__ __launch_bounds__(256) void softmax_k(const int* __restrict__ ei,
                                                 const int* __restrict__ offs,
                                                 const int* __restrict__ ebuf,
                                                 const float* __restrict__ al_s,
                                                 const float* __restrict__ al_d,
                                                 float* __restrict__ alpha,
                                                 int H) {
    int idx = blockIdx.x * 4 + (threadIdx.x >> 6);
    if (idx >= NN * H) return;
    int lane = threadIdx.x & 63;
    int n = idx / H, h = idx - n * H;
    int base = offs[n], cnt = offs[n + 1] - base;
    float ad = al_d[n * H + h];

    float m = -FLT_MAX;
    for (int i = lane; i < cnt; i += 64) {
        int eid = ebuf[base + i];
        int src = (eid < EE) ? ei[eid] : (eid - EE);
        float l = al_s[src * H + h] + ad;
        l = (l < 0.f) ? 0.2f * l : l;
        m = fmaxf(m, l);
    }
    for (int o = 32; o > 0; o >>= 1) m = fmaxf(m, __shfl_xor(m, o, 64));

    float s = 0.f;
    for (int i = lane; i < cnt; i += 64) {
        int eid = ebuf[base + i];
        int src = (eid < EE) ? ei[eid] : (eid - EE);
        float l = al_s[src * H + h] + ad;
        l = (l < 0.f) ? 0.2f * l : l;
        float p = __expf(l - m);
        s += p;
        alpha[(size_t)eid * 6 + h] = p;
    }
    for (int o = 32; o > 0; o >>= 1) s += __shfl_xor(s, o, 64);
    float rinv = 1.f / (s + 1e-16f);
    for (int i = lane; i < cnt; i += 64) {
        int eid = ebuf[base + i];
        alpha[(size_t)eid * 6 + h] *= rinv;
    }
}

// ------------------------------------------------------------ aggregation
// out[n, h*256+c] += sum_e alpha[e,h] * hfeat[src_e, h*256+c]  (one block per (n,h))
__global__ __launch_bounds__(256) void agg_concat_k(const int* __restrict__ ei,
                                                    const int* __restrict__ offs,
                                                    const int* __restrict__ ebuf,
                                                    const float* __restrict__ alpha,
                                                    const float* __restrict__ hfeat,
                                                    float* __restrict__ out,
                                                    int H) {
    __shared__ int   s_src[128];
    __shared__ float s_a[128];
    int b = blockIdx.x;
    int n = b / H, h = b - n * H;
    int c = threadIdx.x;
    int base = offs[n], cnt = offs[n + 1] - base;
    int HC = H * 256;
    float acc = 0.f;
    for (int chunk = 0; chunk < cnt; chunk += 128) {
        int mcnt = min(128, cnt - chunk);
        if (c < mcnt) {
            int eid = ebuf[base + chunk + c];
            s_src[c] = (eid < EE) ? ei[eid] : (eid - EE);
            s_a[c]   = alpha[(size_t)eid * 6 + h];
        }
        __syncthreads();
        for (int i = 0; i < mcnt; i++)
            acc += s_a[i] * hfeat[(size_t)s_src[i] * HC + h * 256 + c];
        __syncthreads();
    }
    out[(size_t)n * HC + h * 256 + c] += acc;
}

// layer 3: mean over 6 heads into 256 cols (one block per node)
__global__ __launch_bounds__(256) void agg_mean_k(const int* __restrict__ ei,
                                                  const int* __restrict__ offs,
                                                  const int* __restrict__ ebuf,
                                                  const float* __restrict__ alpha,
                                                  const float* __restrict__ hfeat,
                                                  float* __restrict__ out) {
    __shared__ int   s_src[128];
    __shared__ float s_a[128 * 6];
    int n = blockIdx.x;
    int c = threadIdx.x;
    int base = offs[n], cnt = offs[n + 1] - base;
    float acc = 0.f;
    for (int chunk = 0; chunk < cnt; chunk += 128) {
        int mcnt = min(128, cnt - chunk);
        if (c < mcnt) {
            int eid = ebuf[base + chunk + c];
            s_src[c] = (eid < EE) ? ei[eid] : (eid - EE);
#pragma unroll
            for (int h = 0; h < 6; h++) s_a[h * 128 + c] = alpha[(size_t)eid * 6 + h];
        }
        __syncthreads();
        for (int i = 0; i < mcnt; i++) {
            const float* hp = hfeat + (size_t)s_src[i] * 1536 + c;
#pragma unroll
            for (int h = 0; h < 6; h++) acc += s_a[h * 128 + i] * hp[h * 256];
        }
        __syncthreads();
    }
    out[(size_t)n * 256 + c] += acc * (1.f / 6.f);
}

// ------------------------------------------------------------------- ELU
__global__ __launch_bounds__(256) void elu_k(float* __restrict__ buf, int n4) {
    int i = blockIdx.x * 256 + threadIdx.x;
    if (i < n4) {
        float4 v = reinterpret_cast<float4*>(buf)[i];
        v.x = (v.x > 0.f) ? v.x : expf(v.x) - 1.f;
        v.y = (v.y > 0.f) ? v.y : expf(v.y) - 1.f;
        v.z = (v.z > 0.f) ? v.z : expf(v.z) - 1.f;
        v.w = (v.w > 0.f) ? v.w : expf(v.w) - 1.f;
        reinterpret_cast<float4*>(buf)[i] = v;
    }
}

// ------------------------------------------------------------------ driver
extern "C" void kernel_launch(void* const* d_in, const int* in_sizes, int n_in,
                              void* d_out, int out_size, void* d_ws, size_t ws_size,
                              hipStream_t stream) {
    const float* x   = (const float*)d_in[0];
    const int*   ei  = (const int*)d_in[1];
    const float* W1  = (const float*)d_in[2];
    const float* a1s = (const float*)d_in[3];
    const float* a1d = (const float*)d_in[4];
    const float* b1  = (const float*)d_in[5];
    const float* S1w = (const float*)d_in[6];
    const float* S1b = (const float*)d_in[7];
    const float* W2  = (const float*)d_in[8];
    const float* a2s = (const float*)d_in[9];
    const float* a2d = (const float*)d_in[10];
    const float* b2  = (const float*)d_in[11];
    const float* S2w = (const float*)d_in[12];
    const float* S2b = (const float*)d_in[13];
    const float* W3  = (const float*)d_in[14];
    const float* a3s = (const float*)d_in[15];
    const float* a3d = (const float*)d_in[16];
    const float* b3  = (const float*)d_in[17];
    const float* S3w = (const float*)d_in[18];
    const float* S3b = (const float*)d_in[19];
    float* out = (float*)d_out;

    float* ws = (float*)d_ws;
    size_t o = 0;
    float* hfeat = ws + o; o += (size_t)NN * 1536;
    float* bufA  = ws + o; o += (size_t)NN * 1024;
    float* bufB  = ws + o; o += (size_t)NN * 1024;
    float* alpha = ws + o; o += (size_t)ETOT * 6;
    float* als   = ws + o; o += (size_t)NN * 6;
    float* ald   = ws + o; o += (size_t)NN * 6;
    int* deg  = (int*)(ws + o);
    int* offs = deg + NN;
    int* pos  = offs + NN + 1;
    int* ebuf = pos + NN;

    // ---- CSR by dst (shared by all 3 layers)
    hipMemsetAsync(deg, 0, NN * sizeof(int), stream);
    count_deg_k<<<(ETOT + 255) / 256, 256, 0, stream>>>(ei, deg);
    scan_k<<<1, 1024, 0, stream>>>(deg, offs, pos);
    scatter_k<<<(ETOT + 255) / 256, 256, 0, stream>>>(ei, pos, ebuf);

    const int gy = (NN + BM - 1) / BM;   // 79

    // ---- Layer 1: in=x [N,128], H=4, out 1024
    gemm_k<false><<<dim3(1024 / BN, gy), 256, 0, stream>>>(x, W1, hfeat, nullptr, nullptr, NN, 128, 1024);
    gemm_k<true ><<<dim3(1024 / BN, gy), 256, 0, stream>>>(x, S1w, bufA, S1b, b1, NN, 128, 1024);
    att_k<<<(NN * 4 + 3) / 4, 256, 0, stream>>>(hfeat, a1s, a1d, als, ald, 4, 1024);
    softmax_k<<<(NN * 4 + 3) / 4, 256, 0, stream>>>(ei, offs, ebuf, als, ald, alpha, 4);
    agg_concat_k<<<NN * 4, 256, 0, stream>>>(ei, offs, ebuf, alpha, hfeat, bufA, 4);
    elu_k<<<(NN * 1024 / 4 + 255) / 256, 256, 0, stream>>>(bufA, NN * 1024 / 4);

    // ---- Layer 2: in=bufA [N,1024], H=4, out 1024
    gemm_k<false><<<dim3(1024 / BN, gy), 256, 0, stream>>>(bufA, W2, hfeat, nullptr, nullptr, NN, 1024, 1024);
    gemm_k<true ><<<dim3(1024 / BN, gy), 256, 0, stream>>>(bufA, S2w, bufB, S2b, b2, NN, 1024, 1024);
    att_k<<<(NN * 4 + 3) / 4, 256, 0, stream>>>(hfeat, a2s, a2d, als, ald, 4, 1024);
    softmax_k<<<(NN * 4 + 3) / 4, 256, 0, stream>>>(ei, offs, ebuf, als, ald, alpha, 4);
    agg_concat_k<<<NN * 4, 256, 0, stream>>>(ei, offs, ebuf, alpha, hfeat, bufB, 4);
    elu_k<<<(NN * 1024 / 4 + 255) / 256, 256, 0, stream>>>(bufB, NN * 1024 / 4);

    // ---- Layer 3: in=bufB [N,1024], H=6, mean -> 256
    gemm_k<false><<<dim3(1536 / BN, gy), 256, 0, stream>>>(bufB, W3, hfeat, nullptr, nullptr, NN, 1024, 1536);
    gemm_k<true ><<<dim3(256 / BN, gy), 256, 0, stream>>>(bufB, S3w, out, S3b, b3, NN, 1024, 256);
    att_k<<<(NN * 6 + 3) / 4, 256, 0, stream>>>(hfeat, a3s, a3d, als, ald, 6, 1536);
    softmax_k<<<(NN * 6 + 3) / 4, 256, 0, stream>>>(ei, offs, ebuf, als, ald, alpha, 6);
    agg_mean_k<<<NN, 256, 0, stream>>>(ei, offs, ebuf, alpha, hfeat, out);
}

// Round 2
// 792.130 us; speedup vs baseline: 2.3209x; 2.3209x over previous
//
#include <hip/hip_runtime.h>
#include <cfloat>
#include <cmath>
#include <cstdint>

#define NN 10000
#define EE 160000
#define ETOT 170000   // EE + NN self loops
#define MPAD 10112    // 79*128

typedef _Float16 f16;
typedef __attribute__((ext_vector_type(8))) _Float16 f16x8;
typedef __attribute__((ext_vector_type(4))) float f32x4;

// ---------------------------------------------------------------- CSR build
__global__ __launch_bounds__(256) void count_deg_k(const int* __restrict__ ei,
                                                   int* __restrict__ deg) {
    int e = blockIdx.x * 256 + threadIdx.x;
    if (e < ETOT) {
        int dst = (e < EE) ? ei[EE + e] : (e - EE);
        atomicAdd(&deg[dst], 1);
    }
}

__global__ __launch_bounds__(1024) void scan_k(const int* __restrict__ deg,
                                               int* __restrict__ offs,
                                               int* __restrict__ pos) {
    __shared__ int s[1024];
    __shared__ int carry_sh;
    const int tid = threadIdx.x;
    if (tid == 0) carry_sh = 0;
    __syncthreads();
    for (int base = 0; base < NN; base += 1024) {
        int i = base + tid;
        int v = (i < NN) ? deg[i] : 0;
        s[tid] = v;
        __syncthreads();
        for (int d = 1; d < 1024; d <<= 1) {
            int t = (tid >= d) ? s[tid - d] : 0;
            __syncthreads();
            s[tid] += t;
            __syncthreads();
        }
        int total = s[1023];
        int carry = carry_sh;
        if (i < NN) {
            offs[i + 1] = carry + s[tid];
            pos[i]      = carry + s[tid] - v;
        }
        __syncthreads();
        if (tid == 0) carry_sh = carry + total;
        __syncthreads();
    }
    if (tid == 0) offs[0] = 0;
}

__global__ __launch_bounds__(256) void scatter_k(const int* __restrict__ ei,
                                                 int* __restrict__ pos,
                                                 int* __restrict__ ebuf) {
    int e = blockIdx.x * 256 + threadIdx.x;
    if (e < ETOT) {
        int dst = (e < EE) ? ei[EE + e] : (e - EE);
        int p = atomicAdd(&pos[dst], 1);
        ebuf[p] = e;
    }
}

// --------------------------------------------------- fp32 -> fp16 hi/lo tiled
// Tiled layout: tile (blk128 x 32k) of 8KB; within tile: row r (0..127) at
// r*64 bytes, 16B chunk ko (0..3) stored at slot ko ^ ((r>>1)&3)  (2-way-free
// LDS bank pattern on ds_read_b128 after a linear global_load_lds copy).
__device__ __forceinline__ int swz(int r, int ko) { return ko ^ ((r >> 1) & 3); }

template <bool DOELU>
__global__ __launch_bounds__(256) void convA_k(const float* __restrict__ A,
                                               f16* __restrict__ hi,
                                               f16* __restrict__ lo,
                                               int M, int K, int kshift) {
    int idx = blockIdx.x * 256 + threadIdx.x;
    int row = idx >> kshift;              // padded row
    int kc  = idx & ((1 << kshift) - 1);  // 8-elem chunk along K
    float v[8];
    if (row < M) {
        const float* p = A + (size_t)row * K + kc * 8;
        float4 f0 = *(const float4*)p, f1 = *(const float4*)(p + 4);
        v[0]=f0.x; v[1]=f0.y; v[2]=f0.z; v[3]=f0.w;
        v[4]=f1.x; v[5]=f1.y; v[6]=f1.z; v[7]=f1.w;
        if (DOELU) {
#pragma unroll
            for (int i = 0; i < 8; i++) v[i] = (v[i] > 0.f) ? v[i] : expf(v[i]) - 1.f;
        }
    } else {
#pragma unroll
        for (int i = 0; i < 8; i++) v[i] = 0.f;
    }
    int mblk = row >> 7, r = row & 127;
    int kblk = kc >> 2,  ko = kc & 3;
    int KB = K >> 5;
    size_t off = ((size_t)(mblk * KB + kblk)) * 4096 + r * 32 + swz(r, ko) * 8;
    f16x8 h, l;
#pragma unroll
    for (int i = 0; i < 8; i++) {
        f16 hv = (f16)v[i];
        h[i] = hv;
        l[i] = (f16)(v[i] - (float)hv);
    }
    *(f16x8*)(hi + off) = h;
    *(f16x8*)(lo + off) = l;
}

// B [K,NcSrc] row-major fp32 -> transposed tiled fp16 hi/lo ([col][k] rows)
__global__ __launch_bounds__(256) void convB_k(const float* __restrict__ B,
                                               f16* __restrict__ hi,
                                               f16* __restrict__ lo,
                                               int NcSrc, int colOff, int KB) {
    int n  = blockIdx.x * 256 + threadIdx.x;  // source column
    int kc = blockIdx.y;                       // 8-elem chunk along K
    const float* p = B + (size_t)(kc * 8) * NcSrc + n;
    int gcol = colOff + n;
    int nblk = gcol >> 7, r = gcol & 127;
    int kblk = kc >> 2,  ko = kc & 3;
    size_t off = ((size_t)(nblk * KB + kblk)) * 4096 + r * 32 + swz(r, ko) * 8;
    f16x8 h, l;
#pragma unroll
    for (int i = 0; i < 8; i++) {
        float v = p[(size_t)i * NcSrc];
        f16 hv = (f16)v;
        h[i] = hv;
        l[i] = (f16)(v - (float)hv);
    }
    *(f16x8*)(hi + off) = h;
    *(f16x8*)(lo + off) = l;
}

// ------------------------------------------------------- split-fp16 MFMA GEMM
// C = A*B, A = Ahi+Alo, B = Bhi+Blo; 3-term product (drop Alo*Blo, ~2^-22).
// 128x128 tile, 4 waves (2x2), each wave 64x64 via 4x4 frags of 16x16x32.
// Columns nblk < NB1 -> C1 (+ fp16 shadow copy); nblk >= NB1 -> C2 + biases.
__device__ __forceinline__ void gl_lds16(const void* g, void* l) {
    __builtin_amdgcn_global_load_lds(
        (const __attribute__((address_space(1))) uint32_t*)g,
        (__attribute__((address_space(3))) uint32_t*)l, 16, 0, 0);
}

__global__ __launch_bounds__(256) void mm_k(const f16* __restrict__ Ahi,
                                            const f16* __restrict__ Alo,
                                            const f16* __restrict__ Bhi,
                                            const f16* __restrict__ Blo,
                                            float* __restrict__ C1,
                                            float* __restrict__ C2,
                                            f16* __restrict__ C1h,
                                            const float* __restrict__ bias1,
                                            const float* __restrict__ bias2,
                                            int M, int KB, int NB1, int N1, int N2) {
    __shared__ __align__(16) char lds[32768];  // Ahi|Alo|Bhi|Blo tiles, 8KB each
    const int tid = threadIdx.x;
    const int mblk = blockIdx.y, nblk = blockIdx.x;
    const int lane = tid & 63, w = tid >> 6;
    const int wr = w >> 1, wc = w & 1;
    const int kg = lane >> 4, l15 = lane & 15;

    int offA[4], offB[4];
#pragma unroll
    for (int t = 0; t < 4; t++) {
        int ra = wr * 64 + t * 16 + l15;
        offA[t] = ra * 64 + swz(ra, kg) * 16;
        int rb = wc * 64 + t * 16 + l15;
        offB[t] = 16384 + rb * 64 + swz(rb, kg) * 16;
    }

    const char* gAh = (const char*)Ahi + (size_t)mblk * KB * 8192;
    const char* gAl = (const char*)Alo + (size_t)mblk * KB * 8192;
    const char* gBh = (const char*)Bhi + (size_t)nblk * KB * 8192;
    const char* gBl = (const char*)Blo + (size_t)nblk * KB * 8192;

    f32x4 acc[4][4];
#pragma unroll
    for (int i = 0; i < 4; i++)
#pragma unroll
        for (int j = 0; j < 4; j++) acc[i][j] = (f32x4){0.f, 0.f, 0.f, 0.f};

    for (int kb = 0; kb < KB; kb++) {
        const size_t tk = (size_t)kb * 8192;
        const int t16 = tid * 16;
        gl_lds16(gAh + tk + t16,        lds + t16);
        gl_lds16(gAh + tk + 4096 + t16, lds + 4096 + t16);
        gl_lds16(gAl + tk + t16,        lds + 8192 + t16);
        gl_lds16(gAl + tk + 4096 + t16, lds + 12288 + t16);
        gl_lds16(gBh + tk + t16,        lds + 16384 + t16);
        gl_lds16(gBh + tk + 4096 + t16, lds + 20480 + t16);
        gl_lds16(gBl + tk + t16,        lds + 24576 + t16);
        gl_lds16(gBl + tk + 4096 + t16, lds + 28672 + t16);
        __syncthreads();   // compiler drains vmcnt before s_barrier

        f16x8 ahi[4], alo[4], bhi[4], blo[4];
#pragma unroll
        for (int t = 0; t < 4; t++) {
            ahi[t] = *(const f16x8*)(lds + offA[t]);
            alo[t] = *(const f16x8*)(lds + 8192 + offA[t]);
            bhi[t] = *(const f16x8*)(lds + offB[t]);
            blo[t] = *(const f16x8*)(lds + 8192 + offB[t]);
        }
#pragma unroll
        for (int i = 0; i < 4; i++)
#pragma unroll
            for (int j = 0; j < 4; j++) {
                acc[i][j] = __builtin_amdgcn_mfma_f32_16x16x32_f16(ahi[i], bhi[j], acc[i][j], 0, 0, 0);
                acc[i][j] = __builtin_amdgcn_mfma_f32_16x16x32_f16(alo[i], bhi[j], acc[i][j], 0, 0, 0);
                acc[i][j] = __builtin_amdgcn_mfma_f32_16x16x32_f16(ahi[i], blo[j], acc[i][j], 0, 0, 0);
            }
        __syncthreads();
    }

    // epilogue: D row=(lane>>4)*4+q, col=lane&15 within each 16x16 frag
    const int rowBase = mblk * 128 + wr * 64;
    const int colBase = nblk * 128 + wc * 64;
    if (nblk < NB1) {
#pragma unroll
        for (int i = 0; i < 4; i++)
#pragma unroll
            for (int j = 0; j < 4; j++) {
                int col = colBase + j * 16 + l15;
#pragma unroll
                for (int q = 0; q < 4; q++) {
                    int row = rowBase + i * 16 + kg * 4 + q;
                    if (row < M) {
                        float v = acc[i][j][q];
                        C1[(size_t)row * N1 + col]  = v;
                        C1h[(size_t)row * N1 + col] = (f16)v;
                    }
                }
            }
    } else {
        const int cb2 = NB1 * 128;
#pragma unroll
        for (int i = 0; i < 4; i++)
#pragma unroll
            for (int j = 0; j < 4; j++) {
                int c2 = colBase + j * 16 + l15 - cb2;
                float bsum = bias1[c2] + bias2[c2];
#pragma unroll
                for (int q = 0; q < 4; q++) {
                    int row = rowBase + i * 16 + kg * 4 + q;
                    if (row < M) C2[(size_t)row * N2 + c2] = acc[i][j][q] + bsum;
                }
            }
    }
}

// ------------------------------------------------------- attention logits
__global__ __launch_bounds__(256) void att_k(const float* __restrict__ hfeat,
                                             const float* __restrict__ a_s,
                                             const float* __restrict__ a_d,
                                             float* __restrict__ al_s,
                                             float* __restrict__ al_d,
                                             int H, int HC) {
    int idx = blockIdx.x * 4 + (threadIdx.x >> 6);
    if (idx >= NN * H) return;
    int lane = threadIdx.x & 63;
    int n = idx / H, h = idx - n * H;
    const float4 hv = *reinterpret_cast<const float4*>(hfeat + (size_t)n * HC + h * 256 + lane * 4);
    const float4 sv = *reinterpret_cast<const float4*>(a_s + h * 256 + lane * 4);
    const float4 dv = *reinterpret_cast<const float4*>(a_d + h * 256 + lane * 4);
    float ss = hv.x * sv.x + hv.y * sv.y + hv.z * sv.z + hv.w * sv.w;
    float sd = hv.x * dv.x + hv.y * dv.y + hv.z * dv.z + hv.w * dv.w;
    for (int o = 32; o > 0; o >>= 1) {
        ss += __shfl_xor(ss, o, 64);
        sd += __shfl_xor(sd, o, 64);
    }
    if (lane == 0) { al_s[idx] = ss; al_d[idx] = sd; }
}

// --------------------------------------------------------------- softmax
__global__ __launch_bounds__(256) void softmax_k(const int* __restrict__ ei,
                                                 const int* __restrict__ offs,
                                                 const int* __restrict__ ebuf,
                                                 const float* __restrict__ al_s,
                                                 const float* __restrict__ al_d,
                                                 float* __restrict__ alpha,
                                                 int H) {
    int idx = blockIdx.x * 4 + (threadIdx.x >> 6);
    if (idx >= NN * H) return;
    int lane = threadIdx.x & 63;
    int n = idx / H, h = idx - n * H;
    int base = offs[n], cnt = offs[n + 1] - base;
    float ad = al_d[n * H + h];

    float m = -FLT_MAX;
    for (int i = lane; i < cnt; i += 64) {
        int eid = ebuf[base + i];
        int src = (eid < EE) ? ei[eid] : (eid - EE);
        float l = al_s[src * H + h] + ad;
        l = (l < 0.f) ? 0.2f * l : l;
        m = fmaxf(m, l);
    }
    for (int o = 32; o > 0; o >>= 1) m = fmaxf(m, __shfl_xor(m, o, 64));

    float s = 0.f;
    for (int i = lane; i < cnt; i += 64) {
        int eid = ebuf[base + i];
        int src = (eid < EE) ? ei[eid] : (eid - EE);
        float l = al_s[src * H + h] + ad;
        l = (l < 0.f) ? 0.2f * l : l;
        float p = __expf(l - m);
        s += p;
        alpha[(size_t)eid * 6 + h] = p;
    }
    for (int o = 32; o > 0; o >>= 1) s += __shfl_xor(s, o, 64);
    float rinv = 1.f / (s + 1e-16f);
    for (int i = lane; i < cnt; i += 64) {
        int eid = ebuf[base + i];
        alpha[(size_t)eid * 6 + h] *= rinv;
    }
}

// ------------------------------------------------------------ aggregation
__global__ __launch_bounds__(256) void agg_concat_k(const int* __restrict__ ei,
                                                    const int* __restrict__ offs,
                                                    const int* __restrict__ ebuf,
                                                    const float* __restrict__ alpha,
                                                    const f16* __restrict__ hfeat,
                                                    float* __restrict__ out,
                                                    int H) {
    __shared__ int   s_src[128];
    __shared__ float s_a[128];
    int b = blockIdx.x;
    int n = b / H, h = b - n * H;
    int c = threadIdx.x;
    int base = offs[n], cnt = offs[n + 1] - base;
    int HC = H * 256;
    float acc = 0.f;
    for (int chunk = 0; chunk < cnt; chunk += 128) {
        int mcnt = min(128, cnt - chunk);
        if (c < mcnt) {
            int eid = ebuf[base + chunk + c];
            s_src[c] = (eid < EE) ? ei[eid] : (eid - EE);
            s_a[c]   = alpha[(size_t)eid * 6 + h];
        }
        __syncthreads();
        for (int i = 0; i < mcnt; i++)
            acc += s_a[i] * (float)hfeat[(size_t)s_src[i] * HC + h * 256 + c];
        __syncthreads();
    }
    out[(size_t)n * HC + h * 256 + c] += acc;
}

__global__ __launch_bounds__(256) void agg_mean_k(const int* __restrict__ ei,
                                                  const int* __restrict__ offs,
                                                  const int* __restrict__ ebuf,
                                                  const float* __restrict__ alpha,
                                                  const f16* __restrict__ hfeat,
                                                  float* __restrict__ out) {
    __shared__ int   s_src[128];
    __shared__ float s_a[128 * 6];
    int n = blockIdx.x;
    int c = threadIdx.x;
    int base = offs[n], cnt = offs[n + 1] - base;
    float acc = 0.f;
    for (int chunk = 0; chunk < cnt; chunk += 128) {
        int mcnt = min(128, cnt - chunk);
        if (c < mcnt) {
            int eid = ebuf[base + chunk + c];
            s_src[c] = (eid < EE) ? ei[eid] : (eid - EE);
#pragma unroll
            for (int h = 0; h < 6; h++) s_a[h * 128 + c] = alpha[(size_t)eid * 6 + h];
        }
        __syncthreads();
        for (int i = 0; i < mcnt; i++) {
            const f16* hp = hfeat + (size_t)s_src[i] * 1536 + c;
#pragma unroll
            for (int h = 0; h < 6; h++) acc += s_a[h * 128 + i] * (float)hp[h * 256];
        }
        __syncthreads();
    }
    out[(size_t)n * 256 + c] += acc * (1.f / 6.f);
}

// ------------------------------------------------------------------ driver
extern "C" void kernel_launch(void* const* d_in, const int* in_sizes, int n_in,
                              void* d_out, int out_size, void* d_ws, size_t ws_size,
                              hipStream_t stream) {
    const float* x   = (const float*)d_in[0];
    const int*   ei  = (const int*)d_in[1];
    const float* W1  = (const float*)d_in[2];
    const float* a1s = (const float*)d_in[3];
    const float* a1d = (const float*)d_in[4];
    const float* b1  = (const float*)d_in[5];
    const float* S1w = (const float*)d_in[6];
    const float* S1b = (const float*)d_in[7];
    const float* W2  = (const float*)d_in[8];
    const float* a2s = (const float*)d_in[9];
    const float* a2d = (const float*)d_in[10];
    const float* b2  = (const float*)d_in[11];
    const float* S2w = (const float*)d_in[12];
    const float* S2b = (const float*)d_in[13];
    const float* W3  = (const float*)d_in[14];
    const float* a3s = (const float*)d_in[15];
    const float* a3d = (const float*)d_in[16];
    const float* b3  = (const float*)d_in[17];
    const float* S3w = (const float*)d_in[18];
    const float* S3b = (const float*)d_in[19];
    float* out = (float*)d_out;

    float* ws = (float*)d_ws;
    size_t o = 0;
    float* hfeat = ws + o; o += (size_t)NN * 1536;
    float* bufA  = ws + o; o += (size_t)NN * 1024;
    float* bufB  = ws + o; o += (size_t)NN * 1024;
    float* alpha = ws + o; o += (size_t)ETOT * 6;
    float* als   = ws + o; o += (size_t)NN * 6;
    float* ald   = ws + o; o += (size_t)NN * 6;
    f16* hfeat16 = (f16*)(ws + o); o += (size_t)NN * 1536 / 2;
    f16* AhiT = (f16*)(ws + o); o += (size_t)MPAD * 1024 / 2;
    f16* AloT = (f16*)(ws + o); o += (size_t)MPAD * 1024 / 2;
    f16* BtH1 = (f16*)(ws + o); o += (size_t)16 * 4 * 4096 / 2;
    f16* BtL1 = (f16*)(ws + o); o += (size_t)16 * 4 * 4096 / 2;
    f16* BtH2 = (f16*)(ws + o); o += (size_t)16 * 32 * 4096 / 2;
    f16* BtL2 = (f16*)(ws + o); o += (size_t)16 * 32 * 4096 / 2;
    f16* BtH3 = (f16*)(ws + o); o += (size_t)14 * 32 * 4096 / 2;
    f16* BtL3 = (f16*)(ws + o); o += (size_t)14 * 32 * 4096 / 2;
    int* deg  = (int*)(ws + o);
    int* offs = deg + NN;
    int* pos  = offs + NN + 1;
    int* ebuf = pos + NN;

    // ---- CSR by dst (shared by all 3 layers)
    hipMemsetAsync(deg, 0, NN * sizeof(int), stream);
    count_deg_k<<<(ETOT + 255) / 256, 256, 0, stream>>>(ei, deg);
    scan_k<<<1, 1024, 0, stream>>>(deg, offs, pos);
    scatter_k<<<(ETOT + 255) / 256, 256, 0, stream>>>(ei, pos, ebuf);

    // ---- weight conversion (merged per-layer B = [W | S])
    convB_k<<<dim3(4, 16),  256, 0, stream>>>(W1,  BtH1, BtL1, 1024, 0,    4);
    convB_k<<<dim3(4, 16),  256, 0, stream>>>(S1w, BtH1, BtL1, 1024, 1024, 4);
    convB_k<<<dim3(4, 128), 256, 0, stream>>>(W2,  BtH2, BtL2, 1024, 0,    32);
    convB_k<<<dim3(4, 128), 256, 0, stream>>>(S2w, BtH2, BtL2, 1024, 1024, 32);
    convB_k<<<dim3(6, 128), 256, 0, stream>>>(W3,  BtH3, BtL3, 1536, 0,    32);
    convB_k<<<dim3(1, 128), 256, 0, stream>>>(S3w, BtH3, BtL3, 256,  1536, 32);

    // ---- Layer 1: A=x [N,128], merged N=2048 (cols 0-1023 -> hfeat, rest skip)
    convA_k<false><<<MPAD * 16 / 256, 256, 0, stream>>>(x, AhiT, AloT, NN, 128, 4);
    mm_k<<<dim3(16, 79), 256, 0, stream>>>(AhiT, AloT, BtH1, BtL1,
                                           hfeat, bufA, hfeat16, S1b, b1,
                                           NN, 4, 8, 1024, 1024);
    att_k<<<(NN * 4 + 3) / 4, 256, 0, stream>>>(hfeat, a1s, a1d, als, ald, 4, 1024);
    softmax_k<<<(NN * 4 + 3) / 4, 256, 0, stream>>>(ei, offs, ebuf, als, ald, alpha, 4);
    agg_concat_k<<<NN * 4, 256, 0, stream>>>(ei, offs, ebuf, alpha, hfeat16, bufA, 4);
    // ELU fused into next convA

    // ---- Layer 2
    convA_k<true><<<MPAD * 128 / 256, 256, 0, stream>>>(bufA, AhiT, AloT, NN, 1024, 7);
    mm_k<<<dim3(16, 79), 256, 0, stream>>>(AhiT, AloT, BtH2, BtL2,
                                           hfeat, bufB, hfeat16, S2b, b2,
                                           NN, 32, 8, 1024, 1024);
    att_k<<<(NN * 4 + 3) / 4, 256, 0, stream>>>(hfeat, a2s, a2d, als, ald, 4, 1024);
    softmax_k<<<(NN * 4 + 3) / 4, 256, 0, stream>>>(ei, offs, ebuf, als, ald, alpha, 4);
    agg_concat_k<<<NN * 4, 256, 0, stream>>>(ei, offs, ebuf, alpha, hfeat16, bufB, 4);

    // ---- Layer 3: merged N=1792 (cols 0-1535 -> hfeat, 1536-1791 -> out+bias)
    convA_k<true><<<MPAD * 128 / 256, 256, 0, stream>>>(bufB, AhiT, AloT, NN, 1024, 7);
    mm_k<<<dim3(14, 79), 256, 0, stream>>>(AhiT, AloT, BtH3, BtL3,
                                           hfeat, out, hfeat16, S3b, b3,
                                           NN, 32, 12, 1536, 256);
    att_k<<<(NN * 6 + 3) / 4, 256, 0, stream>>>(hfeat, a3s, a3d, als, ald, 6, 1536);
    softmax_k<<<(NN * 6 + 3) / 4, 256, 0, stream>>>(ei, offs, ebuf, als, ald, alpha, 6);
    agg_mean_k<<<NN, 256, 0, stream>>>(ei, offs, ebuf, alpha, hfeat16, out);
}

// Round 3
// 720.964 us; speedup vs baseline: 2.5500x; 1.0987x over previous
//
#include <hip/hip_runtime.h>
#include <cfloat>
#include <cmath>
#include <cstdint>

#define NN 10000
#define EE 160000
#define ETOT 170000   // EE + NN self loops
#define MPAD 10112    // 79*128

typedef _Float16 f16;
typedef __attribute__((ext_vector_type(8))) _Float16 f16x8;
typedef __attribute__((ext_vector_type(4))) float f32x4;

// ---------------------------------------------------------------- CSR build
__global__ __launch_bounds__(256) void count_deg_k(const int* __restrict__ ei,
                                                   int* __restrict__ deg) {
    int e = blockIdx.x * 256 + threadIdx.x;
    if (e < ETOT) {
        int dst = (e < EE) ? ei[EE + e] : (e - EE);
        atomicAdd(&deg[dst], 1);
    }
}

// hierarchical exclusive scan of deg[NN] -> offs[NN+1], pos[NN]
__global__ __launch_bounds__(256) void sc1_k(const int* __restrict__ deg,
                                             int* __restrict__ tmp,
                                             int* __restrict__ bsum) {
    __shared__ int s[256];
    int i = blockIdx.x * 256 + threadIdx.x;
    int v = (i < NN) ? deg[i] : 0;
    s[threadIdx.x] = v;
    __syncthreads();
    for (int d = 1; d < 256; d <<= 1) {
        int t = (threadIdx.x >= d) ? s[threadIdx.x - d] : 0;
        __syncthreads();
        s[threadIdx.x] += t;
        __syncthreads();
    }
    if (i < NN) tmp[i] = s[threadIdx.x];
    if (threadIdx.x == 255) bsum[blockIdx.x] = s[255];
}

__global__ __launch_bounds__(64) void sc2_k(const int* __restrict__ bsum,
                                            int* __restrict__ bbase) {
    int lane = threadIdx.x;
    int v = (lane < 40) ? bsum[lane] : 0;
    int incl = v;
    for (int d = 1; d < 64; d <<= 1) {
        int t = __shfl_up(incl, d, 64);
        if (lane >= d) incl += t;
    }
    if (lane < 40) bbase[lane] = incl - v;   // exclusive
}

__global__ __launch_bounds__(256) void sc3_k(const int* __restrict__ deg,
                                             const int* __restrict__ tmp,
                                             const int* __restrict__ bbase,
                                             int* __restrict__ offs,
                                             int* __restrict__ pos) {
    int i = blockIdx.x * 256 + threadIdx.x;
    if (i < NN) {
        int incl = tmp[i] + bbase[blockIdx.x];
        offs[i + 1] = incl;
        pos[i]      = incl - deg[i];
    }
    if (i == 0) offs[0] = 0;
}

// store SRC node id directly (no eid indirection downstream)
__global__ __launch_bounds__(256) void scatter_k(const int* __restrict__ ei,
                                                 int* __restrict__ pos,
                                                 int* __restrict__ esrc) {
    int e = blockIdx.x * 256 + threadIdx.x;
    if (e < ETOT) {
        int dst = (e < EE) ? ei[EE + e] : (e - EE);
        int src = (e < EE) ? ei[e]      : (e - EE);
        int p = atomicAdd(&pos[dst], 1);
        esrc[p] = src;
    }
}

// --------------------------------------------------- fp32 -> fp16 hi/lo tiled
__device__ __forceinline__ int swz(int r, int ko) { return ko ^ ((r >> 1) & 3); }

template <bool DOELU>
__global__ __launch_bounds__(256) void convA_k(const float* __restrict__ A,
                                               f16* __restrict__ hi,
                                               f16* __restrict__ lo,
                                               int M, int K, int kshift) {
    int idx = blockIdx.x * 256 + threadIdx.x;
    int row = idx >> kshift;
    int kc  = idx & ((1 << kshift) - 1);
    float v[8];
    if (row < M) {
        const float* p = A + (size_t)row * K + kc * 8;
        float4 f0 = *(const float4*)p, f1 = *(const float4*)(p + 4);
        v[0]=f0.x; v[1]=f0.y; v[2]=f0.z; v[3]=f0.w;
        v[4]=f1.x; v[5]=f1.y; v[6]=f1.z; v[7]=f1.w;
        if (DOELU) {
#pragma unroll
            for (int i = 0; i < 8; i++) v[i] = (v[i] > 0.f) ? v[i] : expf(v[i]) - 1.f;
        }
    } else {
#pragma unroll
        for (int i = 0; i < 8; i++) v[i] = 0.f;
    }
    int mblk = row >> 7, r = row & 127;
    int kblk = kc >> 2,  ko = kc & 3;
    int KB = K >> 5;
    size_t off = ((size_t)(mblk * KB + kblk)) * 4096 + r * 32 + swz(r, ko) * 8;
    f16x8 h, l;
#pragma unroll
    for (int i = 0; i < 8; i++) {
        f16 hv = (f16)v[i];
        h[i] = hv;
        l[i] = (f16)(v[i] - (float)hv);
    }
    *(f16x8*)(hi + off) = h;
    *(f16x8*)(lo + off) = l;
}

__global__ __launch_bounds__(256) void convB_k(const float* __restrict__ B,
                                               f16* __restrict__ hi,
                                               f16* __restrict__ lo,
                                               int NcSrc, int colOff, int KB) {
    int n  = blockIdx.x * 256 + threadIdx.x;
    int kc = blockIdx.y;
    const float* p = B + (size_t)(kc * 8) * NcSrc + n;
    int gcol = colOff + n;
    int nblk = gcol >> 7, r = gcol & 127;
    int kblk = kc >> 2,  ko = kc & 3;
    size_t off = ((size_t)(nblk * KB + kblk)) * 4096 + r * 32 + swz(r, ko) * 8;
    f16x8 h, l;
#pragma unroll
    for (int i = 0; i < 8; i++) {
        float v = p[(size_t)i * NcSrc];
        f16 hv = (f16)v;
        h[i] = hv;
        l[i] = (f16)(v - (float)hv);
    }
    *(f16x8*)(hi + off) = h;
    *(f16x8*)(lo + off) = l;
}

// ------------------------------------------------------- split-fp16 MFMA GEMM
__device__ __forceinline__ void gl_lds16(const void* g, void* l) {
    __builtin_amdgcn_global_load_lds(
        (const __attribute__((address_space(1))) uint32_t*)g,
        (__attribute__((address_space(3))) uint32_t*)l, 16, 0, 0);
}

__global__ __launch_bounds__(256) void mm_k(const f16* __restrict__ Ahi,
                                            const f16* __restrict__ Alo,
                                            const f16* __restrict__ Bhi,
                                            const f16* __restrict__ Blo,
                                            float* __restrict__ C1,
                                            float* __restrict__ C2,
                                            f16* __restrict__ C1h,
                                            const float* __restrict__ bias1,
                                            const float* __restrict__ bias2,
                                            int M, int KB, int NB1, int N1, int N2) {
    __shared__ __align__(16) char lds[32768];
    const int tid = threadIdx.x;
    const int mblk = blockIdx.y, nblk = blockIdx.x;
    const int lane = tid & 63, w = tid >> 6;
    const int wr = w >> 1, wc = w & 1;
    const int kg = lane >> 4, l15 = lane & 15;

    int offA[4], offB[4];
#pragma unroll
    for (int t = 0; t < 4; t++) {
        int ra = wr * 64 + t * 16 + l15;
        offA[t] = ra * 64 + swz(ra, kg) * 16;
        int rb = wc * 64 + t * 16 + l15;
        offB[t] = 16384 + rb * 64 + swz(rb, kg) * 16;
    }

    const char* gAh = (const char*)Ahi + (size_t)mblk * KB * 8192;
    const char* gAl = (const char*)Alo + (size_t)mblk * KB * 8192;
    const char* gBh = (const char*)Bhi + (size_t)nblk * KB * 8192;
    const char* gBl = (const char*)Blo + (size_t)nblk * KB * 8192;

    f32x4 acc[4][4];
#pragma unroll
    for (int i = 0; i < 4; i++)
#pragma unroll
        for (int j = 0; j < 4; j++) acc[i][j] = (f32x4){0.f, 0.f, 0.f, 0.f};

    for (int kb = 0; kb < KB; kb++) {
        const size_t tk = (size_t)kb * 8192;
        const int t16 = tid * 16;
        gl_lds16(gAh + tk + t16,        lds + t16);
        gl_lds16(gAh + tk + 4096 + t16, lds + 4096 + t16);
        gl_lds16(gAl + tk + t16,        lds + 8192 + t16);
        gl_lds16(gAl + tk + 4096 + t16, lds + 12288 + t16);
        gl_lds16(gBh + tk + t16,        lds + 16384 + t16);
        gl_lds16(gBh + tk + 4096 + t16, lds + 20480 + t16);
        gl_lds16(gBl + tk + t16,        lds + 24576 + t16);
        gl_lds16(gBl + tk + 4096 + t16, lds + 28672 + t16);
        __syncthreads();

        f16x8 ahi[4], alo[4], bhi[4], blo[4];
#pragma unroll
        for (int t = 0; t < 4; t++) {
            ahi[t] = *(const f16x8*)(lds + offA[t]);
            alo[t] = *(const f16x8*)(lds + 8192 + offA[t]);
            bhi[t] = *(const f16x8*)(lds + offB[t]);
            blo[t] = *(const f16x8*)(lds + 8192 + offB[t]);
        }
#pragma unroll
        for (int i = 0; i < 4; i++)
#pragma unroll
            for (int j = 0; j < 4; j++) {
                acc[i][j] = __builtin_amdgcn_mfma_f32_16x16x32_f16(ahi[i], bhi[j], acc[i][j], 0, 0, 0);
                acc[i][j] = __builtin_amdgcn_mfma_f32_16x16x32_f16(alo[i], bhi[j], acc[i][j], 0, 0, 0);
                acc[i][j] = __builtin_amdgcn_mfma_f32_16x16x32_f16(ahi[i], blo[j], acc[i][j], 0, 0, 0);
            }
        __syncthreads();
    }

    const int rowBase = mblk * 128 + wr * 64;
    const int colBase = nblk * 128 + wc * 64;
    if (nblk < NB1) {
#pragma unroll
        for (int i = 0; i < 4; i++)
#pragma unroll
            for (int j = 0; j < 4; j++) {
                int col = colBase + j * 16 + l15;
#pragma unroll
                for (int q = 0; q < 4; q++) {
                    int row = rowBase + i * 16 + kg * 4 + q;
                    if (row < M) {
                        float v = acc[i][j][q];
                        C1[(size_t)row * N1 + col]  = v;
                        C1h[(size_t)row * N1 + col] = (f16)v;
                    }
                }
            }
    } else {
        const int cb2 = NB1 * 128;
#pragma unroll
        for (int i = 0; i < 4; i++)
#pragma unroll
            for (int j = 0; j < 4; j++) {
                int c2 = colBase + j * 16 + l15 - cb2;
                float bsum = bias1[c2] + bias2[c2];
#pragma unroll
                for (int q = 0; q < 4; q++) {
                    int row = rowBase + i * 16 + kg * 4 + q;
                    if (row < M) C2[(size_t)row * N2 + c2] = acc[i][j][q] + bsum;
                }
            }
    }
}

// ------------------------------------------------------- attention logits
__global__ __launch_bounds__(256) void att_k(const float* __restrict__ hfeat,
                                             const float* __restrict__ a_s,
                                             const float* __restrict__ a_d,
                                             float* __restrict__ al_s,
                                             float* __restrict__ al_d,
                                             int H, int HC) {
    int idx = blockIdx.x * 4 + (threadIdx.x >> 6);
    if (idx >= NN * H) return;
    int lane = threadIdx.x & 63;
    int n = idx / H, h = idx - n * H;
    const float4 hv = *reinterpret_cast<const float4*>(hfeat + (size_t)n * HC + h * 256 + lane * 4);
    const float4 sv = *reinterpret_cast<const float4*>(a_s + h * 256 + lane * 4);
    const float4 dv = *reinterpret_cast<const float4*>(a_d + h * 256 + lane * 4);
    float ss = hv.x * sv.x + hv.y * sv.y + hv.z * sv.z + hv.w * sv.w;
    float sd = hv.x * dv.x + hv.y * dv.y + hv.z * dv.z + hv.w * dv.w;
    for (int o = 32; o > 0; o >>= 1) {
        ss += __shfl_xor(ss, o, 64);
        sd += __shfl_xor(sd, o, 64);
    }
    if (lane == 0) { al_s[idx] = ss; al_d[idx] = sd; }
}

// --------------------------- fused edge-softmax + aggregation (per node)
// One block per dst node. Online softmax over edge chunks of 128; edge rows
// staged 8 at a time into LDS via coalesced f16x8; per-thread col ownership.
template <int H, bool MEAN>
__global__ __launch_bounds__(256) void smagg_k(const int* __restrict__ offs,
                                               const int* __restrict__ esrc,
                                               const float* __restrict__ als,
                                               const float* __restrict__ ald,
                                               const f16* __restrict__ hfeat16,
                                               float* __restrict__ out) {
    constexpr int NC  = H * 256;       // row length (f16)
    constexpr int CPR = NC / 8;        // f16x8 chunks per row
    __shared__ f16   rowbuf[8][NC];
    __shared__ float s_l[128 * 9];
    __shared__ float s_p[128 * 9];
    __shared__ int   s_src[128];
    __shared__ float s_m[8], s_s[8], s_scale[8], s_ad[8];

    const int n = blockIdx.x;
    const int tid = threadIdx.x;
    const int base = offs[n], cnt = offs[n + 1] - base;

    if (tid < H) {
        s_m[tid] = -1e30f;
        s_s[tid] = 0.f;
        s_ad[tid] = ald[n * H + tid];
    }
    float acc[H];
#pragma unroll
    for (int h = 0; h < H; h++) acc[h] = 0.f;
    __syncthreads();

    for (int c0 = 0; c0 < cnt; c0 += 128) {
        const int mcnt = min(128, cnt - c0);
        // (a) logits for this chunk
        if (tid < mcnt) {
            int src = esrc[base + c0 + tid];
            s_src[tid] = src;
#pragma unroll
            for (int h = 0; h < H; h++) {
                float l = als[src * H + h] + s_ad[h];
                l = (l < 0.f) ? 0.2f * l : l;
                s_l[tid * 9 + h] = l;
            }
        }
        __syncthreads();
        // (b) per-head running max + sum (32-thread segmented groups)
        if (tid < H * 32) {
            int h = tid >> 5, l5 = tid & 31;
            float m = -1e30f;
            for (int e = l5; e < mcnt; e += 32) m = fmaxf(m, s_l[e * 9 + h]);
            for (int o = 16; o > 0; o >>= 1) m = fmaxf(m, __shfl_xor(m, o, 32));
            float mNew = fmaxf(s_m[h], m);
            float ssum = 0.f;
            for (int e = l5; e < mcnt; e += 32) ssum += __expf(s_l[e * 9 + h] - mNew);
            for (int o = 16; o > 0; o >>= 1) ssum += __shfl_xor(ssum, o, 32);
            if (l5 == 0) {
                float scale = __expf(s_m[h] - mNew);
                s_scale[h] = scale;
                s_s[h] = s_s[h] * scale + ssum;
                s_m[h] = mNew;
            }
        }
        __syncthreads();
        // (c) unnormalized probabilities
        if (tid < mcnt) {
#pragma unroll
            for (int h = 0; h < H; h++)
                s_p[tid * 9 + h] = __expf(s_l[tid * 9 + h] - s_m[h]);
        }
#pragma unroll
        for (int h = 0; h < H; h++) acc[h] *= s_scale[h];
        __syncthreads();
        // (d) aggregate, 8 edge rows per batch
        for (int b0 = 0; b0 < mcnt; b0 += 8) {
            const int nb = min(8, mcnt - b0);
            const int total = nb * CPR;
            for (int idx = tid; idx < total; idx += 256) {
                int e  = idx / CPR;
                int ch = idx - e * CPR;
                int src = s_src[b0 + e];
                *(f16x8*)&rowbuf[e][ch * 8] =
                    *(const f16x8*)&hfeat16[(size_t)src * NC + ch * 8];
            }
            __syncthreads();
            for (int e = 0; e < nb; e++) {
#pragma unroll
                for (int h = 0; h < H; h++)
                    acc[h] += s_p[(b0 + e) * 9 + h] * (float)rowbuf[e][h * 256 + tid];
            }
            __syncthreads();
        }
    }

    // epilogue: normalize and accumulate into out (pre-filled with skip+bias)
    if (MEAN) {
        float v = 0.f;
#pragma unroll
        for (int h = 0; h < H; h++) v += acc[h] / (s_s[h] + 1e-16f);
        out[(size_t)n * 256 + tid] += v * (1.f / 6.f);
    } else {
#pragma unroll
        for (int h = 0; h < H; h++)
            out[(size_t)n * NC + h * 256 + tid] += acc[h] / (s_s[h] + 1e-16f);
    }
}

// ------------------------------------------------------------------ driver
extern "C" void kernel_launch(void* const* d_in, const int* in_sizes, int n_in,
                              void* d_out, int out_size, void* d_ws, size_t ws_size,
                              hipStream_t stream) {
    const float* x   = (const float*)d_in[0];
    const int*   ei  = (const int*)d_in[1];
    const float* W1  = (const float*)d_in[2];
    const float* a1s = (const float*)d_in[3];
    const float* a1d = (const float*)d_in[4];
    const float* b1  = (const float*)d_in[5];
    const float* S1w = (const float*)d_in[6];
    const float* S1b = (const float*)d_in[7];
    const float* W2  = (const float*)d_in[8];
    const float* a2s = (const float*)d_in[9];
    const float* a2d = (const float*)d_in[10];
    const float* b2  = (const float*)d_in[11];
    const float* S2w = (const float*)d_in[12];
    const float* S2b = (const float*)d_in[13];
    const float* W3  = (const float*)d_in[14];
    const float* a3s = (const float*)d_in[15];
    const float* a3d = (const float*)d_in[16];
    const float* b3  = (const float*)d_in[17];
    const float* S3w = (const float*)d_in[18];
    const float* S3b = (const float*)d_in[19];
    float* out = (float*)d_out;

    float* ws = (float*)d_ws;
    size_t o = 0;
    float* hfeat = ws + o; o += (size_t)NN * 1536;
    float* bufA  = ws + o; o += (size_t)NN * 1024;
    float* bufB  = ws + o; o += (size_t)NN * 1024;
    float* als   = ws + o; o += (size_t)NN * 6;
    float* ald   = ws + o; o += (size_t)NN * 6;
    f16* hfeat16 = (f16*)(ws + o); o += (size_t)NN * 1536 / 2;
    f16* AhiT = (f16*)(ws + o); o += (size_t)MPAD * 1024 / 2;
    f16* AloT = (f16*)(ws + o); o += (size_t)MPAD * 1024 / 2;
    f16* BtH1 = (f16*)(ws + o); o += (size_t)16 * 4 * 4096 / 2;
    f16* BtL1 = (f16*)(ws + o); o += (size_t)16 * 4 * 4096 / 2;
    f16* BtH2 = (f16*)(ws + o); o += (size_t)16 * 32 * 4096 / 2;
    f16* BtL2 = (f16*)(ws + o); o += (size_t)16 * 32 * 4096 / 2;
    f16* BtH3 = (f16*)(ws + o); o += (size_t)14 * 32 * 4096 / 2;
    f16* BtL3 = (f16*)(ws + o); o += (size_t)14 * 32 * 4096 / 2;
    int* deg   = (int*)(ws + o);
    int* tmp   = deg + NN;
    int* bsum  = tmp + NN;
    int* bbase = bsum + 64;
    int* offs  = bbase + 64;
    int* pos   = offs + NN + 1;
    int* esrc  = pos + NN;

    // ---- CSR by dst (shared by all 3 layers)
    hipMemsetAsync(deg, 0, NN * sizeof(int), stream);
    count_deg_k<<<(ETOT + 255) / 256, 256, 0, stream>>>(ei, deg);
    sc1_k<<<40, 256, 0, stream>>>(deg, tmp, bsum);
    sc2_k<<<1, 64, 0, stream>>>(bsum, bbase);
    sc3_k<<<40, 256, 0, stream>>>(deg, tmp, bbase, offs, pos);
    scatter_k<<<(ETOT + 255) / 256, 256, 0, stream>>>(ei, pos, esrc);

    // ---- weight conversion (merged per-layer B = [W | S])
    convB_k<<<dim3(4, 16),  256, 0, stream>>>(W1,  BtH1, BtL1, 1024, 0,    4);
    convB_k<<<dim3(4, 16),  256, 0, stream>>>(S1w, BtH1, BtL1, 1024, 1024, 4);
    convB_k<<<dim3(4, 128), 256, 0, stream>>>(W2,  BtH2, BtL2, 1024, 0,    32);
    convB_k<<<dim3(4, 128), 256, 0, stream>>>(S2w, BtH2, BtL2, 1024, 1024, 32);
    convB_k<<<dim3(6, 128), 256, 0, stream>>>(W3,  BtH3, BtL3, 1536, 0,    32);
    convB_k<<<dim3(1, 128), 256, 0, stream>>>(S3w, BtH3, BtL3, 256,  1536, 32);

    // ---- Layer 1
    convA_k<false><<<MPAD * 16 / 256, 256, 0, stream>>>(x, AhiT, AloT, NN, 128, 4);
    mm_k<<<dim3(16, 79), 256, 0, stream>>>(AhiT, AloT, BtH1, BtL1,
                                           hfeat, bufA, hfeat16, S1b, b1,
                                           NN, 4, 8, 1024, 1024);
    att_k<<<(NN * 4 + 3) / 4, 256, 0, stream>>>(hfeat, a1s, a1d, als, ald, 4, 1024);
    smagg_k<4, false><<<NN, 256, 0, stream>>>(offs, esrc, als, ald, hfeat16, bufA);

    // ---- Layer 2
    convA_k<true><<<MPAD * 128 / 256, 256, 0, stream>>>(bufA, AhiT, AloT, NN, 1024, 7);
    mm_k<<<dim3(16, 79), 256, 0, stream>>>(AhiT, AloT, BtH2, BtL2,
                                           hfeat, bufB, hfeat16, S2b, b2,
                                           NN, 32, 8, 1024, 1024);
    att_k<<<(NN * 4 + 3) / 4, 256, 0, stream>>>(hfeat, a2s, a2d, als, ald, 4, 1024);
    smagg_k<4, false><<<NN, 256, 0, stream>>>(offs, esrc, als, ald, hfeat16, bufB);

    // ---- Layer 3
    convA_k<true><<<MPAD * 128 / 256, 256, 0, stream>>>(bufB, AhiT, AloT, NN, 1024, 7);
    mm_k<<<dim3(14, 79), 256, 0, stream>>>(AhiT, AloT, BtH3, BtL3,
                                           hfeat, out, hfeat16, S3b, b3,
                                           NN, 32, 12, 1536, 256);
    att_k<<<(NN * 6 + 3) / 4, 256, 0, stream>>>(hfeat, a3s, a3d, als, ald, 6, 1536);
    smagg_k<6, true><<<NN, 256, 0, stream>>>(offs, esrc, als, ald, hfeat16, out);
}

// Round 4
// 663.530 us; speedup vs baseline: 2.7708x; 1.0866x over previous
//
#include <hip/hip_runtime.h>
#include <cfloat>
#include <cmath>
#include <cstdint>

#define NN 10000
#define EE 160000
#define ETOT 170000   // EE + NN self loops
#define MPAD 10240    // 40 * 256

typedef _Float16 f16;
typedef __attribute__((ext_vector_type(8))) _Float16 f16x8;
typedef __attribute__((ext_vector_type(4))) float f32x4;

// ---------------------------------------------------------------- CSR build
__global__ __launch_bounds__(256) void count_deg_k(const int* __restrict__ ei,
                                                   int* __restrict__ deg) {
    int e = blockIdx.x * 256 + threadIdx.x;
    if (e < ETOT) {
        int dst = (e < EE) ? ei[EE + e] : (e - EE);
        atomicAdd(&deg[dst], 1);
    }
}

__global__ __launch_bounds__(256) void sc1_k(const int* __restrict__ deg,
                                             int* __restrict__ tmp,
                                             int* __restrict__ bsum) {
    __shared__ int s[256];
    int i = blockIdx.x * 256 + threadIdx.x;
    int v = (i < NN) ? deg[i] : 0;
    s[threadIdx.x] = v;
    __syncthreads();
    for (int d = 1; d < 256; d <<= 1) {
        int t = (threadIdx.x >= d) ? s[threadIdx.x - d] : 0;
        __syncthreads();
        s[threadIdx.x] += t;
        __syncthreads();
    }
    if (i < NN) tmp[i] = s[threadIdx.x];
    if (threadIdx.x == 255) bsum[blockIdx.x] = s[255];
}

__global__ __launch_bounds__(64) void sc2_k(const int* __restrict__ bsum,
                                            int* __restrict__ bbase) {
    int lane = threadIdx.x;
    int v = (lane < 40) ? bsum[lane] : 0;
    int incl = v;
    for (int d = 1; d < 64; d <<= 1) {
        int t = __shfl_up(incl, d, 64);
        if (lane >= d) incl += t;
    }
    if (lane < 40) bbase[lane] = incl - v;
}

__global__ __launch_bounds__(256) void sc3_k(const int* __restrict__ deg,
                                             const int* __restrict__ tmp,
                                             const int* __restrict__ bbase,
                                             int* __restrict__ offs,
                                             int* __restrict__ pos) {
    int i = blockIdx.x * 256 + threadIdx.x;
    if (i < NN) {
        int incl = tmp[i] + bbase[blockIdx.x];
        offs[i + 1] = incl;
        pos[i]      = incl - deg[i];
    }
    if (i == 0) offs[0] = 0;
}

__global__ __launch_bounds__(256) void scatter_k(const int* __restrict__ ei,
                                                 int* __restrict__ pos,
                                                 int* __restrict__ esrc) {
    int e = blockIdx.x * 256 + threadIdx.x;
    if (e < ETOT) {
        int dst = (e < EE) ? ei[EE + e] : (e - EE);
        int src = (e < EE) ? ei[e]      : (e - EE);
        int p = atomicAdd(&pos[dst], 1);
        esrc[p] = src;
    }
}

// --------------------------------------------- fp32 -> tiled f16 K-split
// A' = [Ahi | Alo] along K (K' = 2K). Tile = 128 rows x 32 k = 4096 f16 (8KB).
// Within tile: row r at r*64 bytes; 16B chunk ko at slot ko ^ ((r>>1)&3).
__device__ __forceinline__ int swz(int r, int ko) { return ko ^ ((r >> 1) & 3); }

template <bool DOELU>
__global__ __launch_bounds__(256) void convA_k(const float* __restrict__ A,
                                               f16* __restrict__ Adst,
                                               int M, int K, int kshift) {
    int idx = blockIdx.x * 256 + threadIdx.x;
    int row = idx >> kshift;
    int kc  = idx & ((1 << kshift) - 1);
    float v[8];
    if (row < M) {
        const float* p = A + (size_t)row * K + kc * 8;
        float4 f0 = *(const float4*)p, f1 = *(const float4*)(p + 4);
        v[0]=f0.x; v[1]=f0.y; v[2]=f0.z; v[3]=f0.w;
        v[4]=f1.x; v[5]=f1.y; v[6]=f1.z; v[7]=f1.w;
        if (DOELU) {
#pragma unroll
            for (int i = 0; i < 8; i++) v[i] = (v[i] > 0.f) ? v[i] : expf(v[i]) - 1.f;
        }
    } else {
#pragma unroll
        for (int i = 0; i < 8; i++) v[i] = 0.f;
    }
    int mblk = row >> 7, r = row & 127;
    int kblk = kc >> 2,  ko = kc & 3;
    int KB = K >> 5, KB2 = KB * 2;
    size_t inoff = r * 32 + swz(r, ko) * 8;
    f16x8 h, l;
#pragma unroll
    for (int i = 0; i < 8; i++) {
        f16 hv = (f16)v[i];
        h[i] = hv;
        l[i] = (f16)(v[i] - (float)hv);
    }
    *(f16x8*)(Adst + (size_t)(mblk * KB2 + kblk) * 4096 + inoff)      = h;
    *(f16x8*)(Adst + (size_t)(mblk * KB2 + KB + kblk) * 4096 + inoff) = l;
}

// B [K,NcSrc] fp32 -> transposed tiled f16 hi, duplicated along K' halves
__global__ __launch_bounds__(256) void convB_k(const float* __restrict__ B,
                                               f16* __restrict__ Bdst,
                                               int NcSrc, int colOff, int KB) {
    int n  = blockIdx.x * 256 + threadIdx.x;
    int kc = blockIdx.y;
    const float* p = B + (size_t)(kc * 8) * NcSrc + n;
    int gcol = colOff + n;
    int nblk = gcol >> 7, r = gcol & 127;
    int kblk = kc >> 2,  ko = kc & 3;
    int KB2 = KB * 2;
    size_t inoff = r * 32 + swz(r, ko) * 8;
    f16x8 h;
#pragma unroll
    for (int i = 0; i < 8; i++) h[i] = (f16)p[(size_t)i * NcSrc];
    *(f16x8*)(Bdst + (size_t)(nblk * KB2 + kblk) * 4096 + inoff)      = h;
    *(f16x8*)(Bdst + (size_t)(nblk * KB2 + KB + kblk) * 4096 + inoff) = h;
}

// ---------------------------------------------------------- f16 MFMA GEMM
// 256x128 tile, BK=64 (two k32 halves), 8 waves (4 row x 2 col), wave=64x64.
// nblk < NB1: write f16 C1h + fused attention logit partials (atomicAdd).
// nblk >= NB1: write fp32 C2 + bias1 + bias2.
__device__ __forceinline__ void gl_lds16(const void* g, void* l) {
    __builtin_amdgcn_global_load_lds(
        (const __attribute__((address_space(1))) uint32_t*)g,
        (__attribute__((address_space(3))) uint32_t*)l, 16, 0, 0);
}

__global__ __launch_bounds__(512) void mm_k(const f16* __restrict__ Ap,
                                            const f16* __restrict__ Bp,
                                            float* __restrict__ C2,
                                            f16* __restrict__ C1h,
                                            const float* __restrict__ bias1,
                                            const float* __restrict__ bias2,
                                            const float* __restrict__ a_s,
                                            const float* __restrict__ a_d,
                                            float* __restrict__ als,
                                            float* __restrict__ ald,
                                            int M, int KB2, int NB1,
                                            int N1, int N2, int H) {
    __shared__ __align__(16) char lds[49152];   // A: 4x8KB, B: 2x8KB
    const int tid = threadIdx.x;
    const int mblk = blockIdx.y, nblk = blockIdx.x;
    const int lane = tid & 63, w = tid >> 6;
    const int wr = w >> 1, wc = w & 1;
    const int kg = lane >> 4, l15 = lane & 15;

    // frag LDS offsets: A rows wr*64+t*16+l15 (of 256), B rows wc*64+t*16+l15
    int offA[2][4], offB[2][4];
#pragma unroll
    for (int t = 0; t < 4; t++) {
        int ra = wr * 64 + t * 16 + l15;
        int s = ra >> 7, r = ra & 127;
        int rb = wc * 64 + t * 16 + l15;
#pragma unroll
        for (int hh = 0; hh < 2; hh++) {
            offA[hh][t] = hh * 16384 + s * 8192 + r * 64 + swz(r, kg) * 16;
            offB[hh][t] = 32768 + hh * 8192 + rb * 64 + swz(rb, kg) * 16;
        }
    }

    const char* gA = (const char*)Ap;
    const char* gB = (const char*)Bp + (size_t)nblk * KB2 * 8192;

    f32x4 acc[4][4];
#pragma unroll
    for (int i = 0; i < 4; i++)
#pragma unroll
        for (int j = 0; j < 4; j++) acc[i][j] = (f32x4){0.f, 0.f, 0.f, 0.f};

    const int nsteps = KB2 >> 1;
    for (int kb = 0; kb < nsteps; kb++) {
        const int t16 = tid * 16;
#pragma unroll
        for (int hh = 0; hh < 2; hh++) {
            int kt = 2 * kb + hh;
#pragma unroll
            for (int s = 0; s < 2; s++)
                gl_lds16(gA + ((size_t)((2 * mblk + s) * KB2 + kt)) * 8192 + t16,
                         lds + hh * 16384 + s * 8192 + t16);
            gl_lds16(gB + (size_t)kt * 8192 + t16, lds + 32768 + hh * 8192 + t16);
        }
        __syncthreads();

#pragma unroll
        for (int hh = 0; hh < 2; hh++) {
            f16x8 a[4], b[4];
#pragma unroll
            for (int t = 0; t < 4; t++) {
                a[t] = *(const f16x8*)(lds + offA[hh][t]);
                b[t] = *(const f16x8*)(lds + offB[hh][t]);
            }
#pragma unroll
            for (int i = 0; i < 4; i++)
#pragma unroll
                for (int j = 0; j < 4; j++)
                    acc[i][j] = __builtin_amdgcn_mfma_f32_16x16x32_f16(a[i], b[j], acc[i][j], 0, 0, 0);
        }
        __syncthreads();
    }

    const int rowBase = mblk * 256 + wr * 64;
    const int colBase = nblk * 128 + wc * 64;
    if (nblk < NB1) {
        // f16 feature write
#pragma unroll
        for (int i = 0; i < 4; i++)
#pragma unroll
            for (int j = 0; j < 4; j++) {
                int col = colBase + j * 16 + l15;
#pragma unroll
                for (int q = 0; q < 4; q++) {
                    int row = rowBase + i * 16 + kg * 4 + q;
                    C1h[(size_t)row * N1 + col] = (f16)acc[i][j][q];
                }
            }
        // fused attention logits: this block covers one head's 128-col half
        const int head = nblk >> 1;
        const int cIn  = (nblk & 1) * 128 + wc * 64;
        float asv[4], adv[4];
#pragma unroll
        for (int j = 0; j < 4; j++) {
            asv[j] = a_s[head * 256 + cIn + j * 16 + l15];
            adv[j] = a_d[head * 256 + cIn + j * 16 + l15];
        }
#pragma unroll
        for (int i = 0; i < 4; i++)
#pragma unroll
            for (int q = 0; q < 4; q++) {
                float vs = acc[i][0][q] * asv[0] + acc[i][1][q] * asv[1]
                         + acc[i][2][q] * asv[2] + acc[i][3][q] * asv[3];
                float vd = acc[i][0][q] * adv[0] + acc[i][1][q] * adv[1]
                         + acc[i][2][q] * adv[2] + acc[i][3][q] * adv[3];
                vs += __shfl_xor(vs, 1); vs += __shfl_xor(vs, 2);
                vs += __shfl_xor(vs, 4); vs += __shfl_xor(vs, 8);
                vd += __shfl_xor(vd, 1); vd += __shfl_xor(vd, 2);
                vd += __shfl_xor(vd, 4); vd += __shfl_xor(vd, 8);
                if (l15 == 0) {
                    int row = rowBase + i * 16 + kg * 4 + q;
                    if (row < M) {
                        atomicAdd(&als[row * H + head], vs);
                        atomicAdd(&ald[row * H + head], vd);
                    }
                }
            }
    } else {
        const int cb2 = NB1 * 128;
#pragma unroll
        for (int i = 0; i < 4; i++)
#pragma unroll
            for (int j = 0; j < 4; j++) {
                int c2 = colBase + j * 16 + l15 - cb2;
                float bsum = bias1[c2] + bias2[c2];
#pragma unroll
                for (int q = 0; q < 4; q++) {
                    int row = rowBase + i * 16 + kg * 4 + q;
                    if (row < M) C2[(size_t)row * N2 + c2] = acc[i][j][q] + bsum;
                }
            }
    }
}

// --------------------------- fused edge-softmax + aggregation (per node)
template <int H, bool MEAN>
__global__ __launch_bounds__(256) void smagg_k(const int* __restrict__ offs,
                                               const int* __restrict__ esrc,
                                               const float* __restrict__ als,
                                               const float* __restrict__ ald,
                                               const f16* __restrict__ hfeat16,
                                               float* __restrict__ out) {
    constexpr int NC = H * 256;
    __shared__ float s_l[128 * 9];
    __shared__ float s_p[128 * 9];
    __shared__ int   s_src[128];
    __shared__ float s_m[8], s_s[8], s_scale[8], s_ad[8];

    const int n = blockIdx.x;
    const int tid = threadIdx.x;
    const int base = offs[n], cnt = offs[n + 1] - base;

    if (tid < H) {
        s_m[tid] = -1e30f;
        s_s[tid] = 0.f;
        s_ad[tid] = ald[n * H + tid];
    }
    float acc[H];
#pragma unroll
    for (int h = 0; h < H; h++) acc[h] = 0.f;
    __syncthreads();

    for (int c0 = 0; c0 < cnt; c0 += 128) {
        const int mcnt = min(128, cnt - c0);
        if (tid < mcnt) {
            int src = esrc[base + c0 + tid];
            s_src[tid] = src;
#pragma unroll
            for (int h = 0; h < H; h++) {
                float l = als[src * H + h] + s_ad[h];
                l = (l < 0.f) ? 0.2f * l : l;
                s_l[tid * 9 + h] = l;
            }
        }
        __syncthreads();
        if (tid < H * 32) {
            int h = tid >> 5, l5 = tid & 31;
            float m = -1e30f;
            for (int e = l5; e < mcnt; e += 32) m = fmaxf(m, s_l[e * 9 + h]);
            for (int o = 16; o > 0; o >>= 1) m = fmaxf(m, __shfl_xor(m, o, 32));
            float mNew = fmaxf(s_m[h], m);
            float ssum = 0.f;
            for (int e = l5; e < mcnt; e += 32) ssum += __expf(s_l[e * 9 + h] - mNew);
            for (int o = 16; o > 0; o >>= 1) ssum += __shfl_xor(ssum, o, 32);
            if (l5 == 0) {
                float scale = __expf(s_m[h] - mNew);
                s_scale[h] = scale;
                s_s[h] = s_s[h] * scale + ssum;
                s_m[h] = mNew;
            }
        }
        __syncthreads();
        if (tid < mcnt) {
#pragma unroll
            for (int h = 0; h < H; h++)
                s_p[tid * 9 + h] = __expf(s_l[tid * 9 + h] - s_m[h]);
        }
#pragma unroll
        for (int h = 0; h < H; h++) acc[h] *= s_scale[h];
        __syncthreads();
        // direct coalesced aggregation: all threads stream each edge's row
        for (int e = 0; e < mcnt; e++) {
            const f16* hp = hfeat16 + (size_t)s_src[e] * NC + tid;
#pragma unroll
            for (int h = 0; h < H; h++)
                acc[h] += s_p[e * 9 + h] * (float)hp[h * 256];
        }
        __syncthreads();
    }

    if (MEAN) {
        float v = 0.f;
#pragma unroll
        for (int h = 0; h < H; h++) v += acc[h] / (s_s[h] + 1e-16f);
        out[(size_t)n * 256 + tid] += v * (1.f / 6.f);
    } else {
#pragma unroll
        for (int h = 0; h < H; h++)
            out[(size_t)n * NC + h * 256 + tid] += acc[h] / (s_s[h] + 1e-16f);
    }
}

// ------------------------------------------------------------------ driver
extern "C" void kernel_launch(void* const* d_in, const int* in_sizes, int n_in,
                              void* d_out, int out_size, void* d_ws, size_t ws_size,
                              hipStream_t stream) {
    const float* x   = (const float*)d_in[0];
    const int*   ei  = (const int*)d_in[1];
    const float* W1  = (const float*)d_in[2];
    const float* a1s = (const float*)d_in[3];
    const float* a1d = (const float*)d_in[4];
    const float* b1  = (const float*)d_in[5];
    const float* S1w = (const float*)d_in[6];
    const float* S1b = (const float*)d_in[7];
    const float* W2  = (const float*)d_in[8];
    const float* a2s = (const float*)d_in[9];
    const float* a2d = (const float*)d_in[10];
    const float* b2  = (const float*)d_in[11];
    const float* S2w = (const float*)d_in[12];
    const float* S2b = (const float*)d_in[13];
    const float* W3  = (const float*)d_in[14];
    const float* a3s = (const float*)d_in[15];
    const float* a3d = (const float*)d_in[16];
    const float* b3  = (const float*)d_in[17];
    const float* S3w = (const float*)d_in[18];
    const float* S3b = (const float*)d_in[19];
    float* out = (float*)d_out;

    float* ws = (float*)d_ws;
    size_t o = 0;
    float* bufA = ws + o; o += (size_t)NN * 1024;
    float* bufB = ws + o; o += (size_t)NN * 1024;
    float* als  = ws + o; o += (size_t)NN * 6;
    float* ald  = ws + o; o += (size_t)NN * 6;
    f16* hfeat16 = (f16*)(ws + o); o += (size_t)MPAD * 1536 / 2;
    f16* At  = (f16*)(ws + o); o += (size_t)MPAD * 2048 / 2;        // K'<=2048
    f16* Bt1 = (f16*)(ws + o); o += (size_t)16 * 8  * 4096 / 2;
    f16* Bt2 = (f16*)(ws + o); o += (size_t)16 * 64 * 4096 / 2;
    f16* Bt3 = (f16*)(ws + o); o += (size_t)14 * 64 * 4096 / 2;
    int* deg   = (int*)(ws + o);
    int* tmp   = deg + NN;
    int* bsum  = tmp + NN;
    int* bbase = bsum + 64;
    int* offs  = bbase + 64;
    int* pos   = offs + NN + 1;
    int* esrc  = pos + NN;

    // ---- CSR by dst (shared by all 3 layers)
    hipMemsetAsync(deg, 0, NN * sizeof(int), stream);
    count_deg_k<<<(ETOT + 255) / 256, 256, 0, stream>>>(ei, deg);
    sc1_k<<<40, 256, 0, stream>>>(deg, tmp, bsum);
    sc2_k<<<1, 64, 0, stream>>>(bsum, bbase);
    sc3_k<<<40, 256, 0, stream>>>(deg, tmp, bbase, offs, pos);
    scatter_k<<<(ETOT + 255) / 256, 256, 0, stream>>>(ei, pos, esrc);

    // ---- weight conversion (merged per-layer B' = [W | S], K-duplicated)
    convB_k<<<dim3(4, 16),  256, 0, stream>>>(W1,  Bt1, 1024, 0,    4);
    convB_k<<<dim3(4, 16),  256, 0, stream>>>(S1w, Bt1, 1024, 1024, 4);
    convB_k<<<dim3(4, 128), 256, 0, stream>>>(W2,  Bt2, 1024, 0,    32);
    convB_k<<<dim3(4, 128), 256, 0, stream>>>(S2w, Bt2, 1024, 1024, 32);
    convB_k<<<dim3(6, 128), 256, 0, stream>>>(W3,  Bt3, 1536, 0,    32);
    convB_k<<<dim3(1, 128), 256, 0, stream>>>(S3w, Bt3, 256,  1536, 32);

    // ---- Layer 1: A=x [N,128] K'=256, N=2048 (8 blk feat | 8 blk skip)
    convA_k<false><<<MPAD * 16 / 256, 256, 0, stream>>>(x, At, NN, 128, 4);
    hipMemsetAsync(als, 0, NN * 12 * sizeof(float), stream);
    mm_k<<<dim3(16, 40), 512, 0, stream>>>(At, Bt1, bufA, hfeat16, S1b, b1,
                                           a1s, a1d, als, ald,
                                           NN, 8, 8, 1024, 1024, 4);
    smagg_k<4, false><<<NN, 256, 0, stream>>>(offs, esrc, als, ald, hfeat16, bufA);

    // ---- Layer 2: K'=2048
    convA_k<true><<<MPAD * 128 / 256, 256, 0, stream>>>(bufA, At, NN, 1024, 7);
    hipMemsetAsync(als, 0, NN * 12 * sizeof(float), stream);
    mm_k<<<dim3(16, 40), 512, 0, stream>>>(At, Bt2, bufB, hfeat16, S2b, b2,
                                           a2s, a2d, als, ald,
                                           NN, 64, 8, 1024, 1024, 4);
    smagg_k<4, false><<<NN, 256, 0, stream>>>(offs, esrc, als, ald, hfeat16, bufB);

    // ---- Layer 3: N=1792 (12 blk feat | 2 blk skip->out), mean over 6 heads
    convA_k<true><<<MPAD * 128 / 256, 256, 0, stream>>>(bufB, At, NN, 1024, 7);
    hipMemsetAsync(als, 0, NN * 12 * sizeof(float), stream);
    mm_k<<<dim3(14, 40), 512, 0, stream>>>(At, Bt3, out, hfeat16, S3b, b3,
                                           a3s, a3d, als, ald,
                                           NN, 64, 12, 1536, 256, 6);
    smagg_k<6, true><<<NN, 256, 0, stream>>>(offs, esrc, als, ald, hfeat16, out);
}

// Round 5
// 646.266 us; speedup vs baseline: 2.8448x; 1.0267x over previous
//
#include <hip/hip_runtime.h>
#include <cfloat>
#include <cmath>
#include <cstdint>

#define NN 10000
#define EE 160000
#define ETOT 170000   // EE + NN self loops
#define MPAD 10112    // 79*128

typedef _Float16 f16;
typedef __attribute__((ext_vector_type(8))) _Float16 f16x8;
typedef __attribute__((ext_vector_type(4))) float f32x4;

// ---------------------------------------------------------------- CSR build
__global__ __launch_bounds__(256) void count_deg_k(const int* __restrict__ ei,
                                                   int* __restrict__ deg) {
    int e = blockIdx.x * 256 + threadIdx.x;
    if (e < ETOT) {
        int dst = (e < EE) ? ei[EE + e] : (e - EE);
        atomicAdd(&deg[dst], 1);
    }
}

__global__ __launch_bounds__(256) void sc1_k(const int* __restrict__ deg,
                                             int* __restrict__ tmp,
                                             int* __restrict__ bsum) {
    __shared__ int s[256];
    int i = blockIdx.x * 256 + threadIdx.x;
    int v = (i < NN) ? deg[i] : 0;
    s[threadIdx.x] = v;
    __syncthreads();
    for (int d = 1; d < 256; d <<= 1) {
        int t = (threadIdx.x >= d) ? s[threadIdx.x - d] : 0;
        __syncthreads();
        s[threadIdx.x] += t;
        __syncthreads();
    }
    if (i < NN) tmp[i] = s[threadIdx.x];
    if (threadIdx.x == 255) bsum[blockIdx.x] = s[255];
}

__global__ __launch_bounds__(64) void sc2_k(const int* __restrict__ bsum,
                                            int* __restrict__ bbase) {
    int lane = threadIdx.x;
    int v = (lane < 40) ? bsum[lane] : 0;
    int incl = v;
    for (int d = 1; d < 64; d <<= 1) {
        int t = __shfl_up(incl, d, 64);
        if (lane >= d) incl += t;
    }
    if (lane < 40) bbase[lane] = incl - v;
}

__global__ __launch_bounds__(256) void sc3_k(const int* __restrict__ deg,
                                             const int* __restrict__ tmp,
                                             const int* __restrict__ bbase,
                                             int* __restrict__ offs,
                                             int* __restrict__ pos) {
    int i = blockIdx.x * 256 + threadIdx.x;
    if (i < NN) {
        int incl = tmp[i] + bbase[blockIdx.x];
        offs[i + 1] = incl;
        pos[i]      = incl - deg[i];
    }
    if (i == 0) offs[0] = 0;
}

__global__ __launch_bounds__(256) void scatter_k(const int* __restrict__ ei,
                                                 int* __restrict__ pos,
                                                 int* __restrict__ esrc) {
    int e = blockIdx.x * 256 + threadIdx.x;
    if (e < ETOT) {
        int dst = (e < EE) ? ei[EE + e] : (e - EE);
        int src = (e < EE) ? ei[e]      : (e - EE);
        int p = atomicAdd(&pos[dst], 1);
        esrc[p] = src;
    }
}

// --------------------------------------------- fp32 -> tiled f16 hi/lo
// Tile = 128 rows x 32 k (8KB). Row r at r*64B; 16B chunk ko at ko^((r>>1)&3).
__device__ __forceinline__ int swz(int r, int ko) { return ko ^ ((r >> 1) & 3); }

template <bool DOELU>
__global__ __launch_bounds__(256) void convA_k(const float* __restrict__ A,
                                               f16* __restrict__ hi,
                                               f16* __restrict__ lo,
                                               int M, int K, int kshift) {
    int idx = blockIdx.x * 256 + threadIdx.x;
    int row = idx >> kshift;
    int kc  = idx & ((1 << kshift) - 1);
    float v[8];
    if (row < M) {
        const float* p = A + (size_t)row * K + kc * 8;
        float4 f0 = *(const float4*)p, f1 = *(const float4*)(p + 4);
        v[0]=f0.x; v[1]=f0.y; v[2]=f0.z; v[3]=f0.w;
        v[4]=f1.x; v[5]=f1.y; v[6]=f1.z; v[7]=f1.w;
        if (DOELU) {
#pragma unroll
            for (int i = 0; i < 8; i++) v[i] = (v[i] > 0.f) ? v[i] : expf(v[i]) - 1.f;
        }
    } else {
#pragma unroll
        for (int i = 0; i < 8; i++) v[i] = 0.f;
    }
    int mblk = row >> 7, r = row & 127;
    int kblk = kc >> 2,  ko = kc & 3;
    int KB = K >> 5;
    size_t off = ((size_t)(mblk * KB + kblk)) * 4096 + r * 32 + swz(r, ko) * 8;
    f16x8 h, l;
#pragma unroll
    for (int i = 0; i < 8; i++) {
        f16 hv = (f16)v[i];
        h[i] = hv;
        l[i] = (f16)(v[i] - (float)hv);
    }
    *(f16x8*)(hi + off) = h;
    *(f16x8*)(lo + off) = l;
}

// B [K,NcSrc] fp32 -> transposed tiled f16 (hi only)
__global__ __launch_bounds__(256) void convB_k(const float* __restrict__ B,
                                               f16* __restrict__ Bdst,
                                               int NcSrc, int colOff, int KB) {
    int n  = blockIdx.x * 256 + threadIdx.x;
    int kc = blockIdx.y;
    const float* p = B + (size_t)(kc * 8) * NcSrc + n;
    int gcol = colOff + n;
    int nblk = gcol >> 7, r = gcol & 127;
    int kblk = kc >> 2,  ko = kc & 3;
    size_t off = ((size_t)(nblk * KB + kblk)) * 4096 + r * 32 + swz(r, ko) * 8;
    f16x8 h;
#pragma unroll
    for (int i = 0; i < 8; i++) h[i] = (f16)p[(size_t)i * NcSrc];
    *(f16x8*)(Bdst + off) = h;
}

// ---------------------------------------------------------- f16 MFMA GEMM
// C = (Ahi+Alo)*Bhi. 128x128 tile, BK=32, 4 waves (2x2), wave = 64x64.
// XCD-aware bijective block swizzle for A-panel L2 locality.
// nblk < NB1: f16 C1h + fused attention logits; else fp32 C2 + biases.
__device__ __forceinline__ void gl_lds16(const void* g, void* l) {
    __builtin_amdgcn_global_load_lds(
        (const __attribute__((address_space(1))) uint32_t*)g,
        (__attribute__((address_space(3))) uint32_t*)l, 16, 0, 0);
}

__global__ __launch_bounds__(256) void mm_k(const f16* __restrict__ Ahi,
                                            const f16* __restrict__ Alo,
                                            const f16* __restrict__ Bhi,
                                            float* __restrict__ C2,
                                            f16* __restrict__ C1h,
                                            const float* __restrict__ bias1,
                                            const float* __restrict__ bias2,
                                            const float* __restrict__ a_s,
                                            const float* __restrict__ a_d,
                                            float* __restrict__ als,
                                            float* __restrict__ ald,
                                            int M, int KB, int NB1,
                                            int N1, int N2, int H) {
    __shared__ __align__(16) char lds[24576];   // Ahi | Alo | Bhi (8KB each)
    const int tid = threadIdx.x;

    // bijective XCD chunking: consecutive remapped ids share mblk on one XCD
    const int nwg  = gridDim.x * gridDim.y;
    const int orig = blockIdx.y * gridDim.x + blockIdx.x;
    const int q = nwg >> 3, rr = nwg & 7;
    const int xcd = orig & 7, rk = orig >> 3;
    const int lin = (xcd < rr ? xcd * (q + 1) : rr * (q + 1) + (xcd - rr) * q) + rk;
    const int mblk = lin / gridDim.x, nblk = lin % gridDim.x;

    const int lane = tid & 63, w = tid >> 6;
    const int wr = w >> 1, wc = w & 1;
    const int kg = lane >> 4, l15 = lane & 15;

    int offA[4], offB[4];
#pragma unroll
    for (int t = 0; t < 4; t++) {
        int ra = wr * 64 + t * 16 + l15;
        offA[t] = ra * 64 + swz(ra, kg) * 16;
        int rb = wc * 64 + t * 16 + l15;
        offB[t] = 16384 + rb * 64 + swz(rb, kg) * 16;
    }

    const char* gAh = (const char*)Ahi + (size_t)mblk * KB * 8192;
    const char* gAl = (const char*)Alo + (size_t)mblk * KB * 8192;
    const char* gBh = (const char*)Bhi + (size_t)nblk * KB * 8192;

    f32x4 acc[4][4];
#pragma unroll
    for (int i = 0; i < 4; i++)
#pragma unroll
        for (int j = 0; j < 4; j++) acc[i][j] = (f32x4){0.f, 0.f, 0.f, 0.f};

    for (int kb = 0; kb < KB; kb++) {
        const size_t tk = (size_t)kb * 8192;
        const int t16 = tid * 16;
        gl_lds16(gAh + tk + t16,        lds + t16);
        gl_lds16(gAh + tk + 4096 + t16, lds + 4096 + t16);
        gl_lds16(gAl + tk + t16,        lds + 8192 + t16);
        gl_lds16(gAl + tk + 4096 + t16, lds + 12288 + t16);
        gl_lds16(gBh + tk + t16,        lds + 16384 + t16);
        gl_lds16(gBh + tk + 4096 + t16, lds + 20480 + t16);
        __syncthreads();

        f16x8 ah[4], al[4], b[4];
#pragma unroll
        for (int t = 0; t < 4; t++) {
            ah[t] = *(const f16x8*)(lds + offA[t]);
            al[t] = *(const f16x8*)(lds + 8192 + offA[t]);
            b[t]  = *(const f16x8*)(lds + offB[t]);
        }
#pragma unroll
        for (int i = 0; i < 4; i++)
#pragma unroll
            for (int j = 0; j < 4; j++) {
                acc[i][j] = __builtin_amdgcn_mfma_f32_16x16x32_f16(ah[i], b[j], acc[i][j], 0, 0, 0);
                acc[i][j] = __builtin_amdgcn_mfma_f32_16x16x32_f16(al[i], b[j], acc[i][j], 0, 0, 0);
            }
        __syncthreads();
    }

    const int rowBase = mblk * 128 + wr * 64;
    const int colBase = nblk * 128 + wc * 64;
    if (nblk < NB1) {
        // f16 feature write (padded rows hold zeros; smagg reads only <NN)
#pragma unroll
        for (int i = 0; i < 4; i++)
#pragma unroll
            for (int j = 0; j < 4; j++) {
                int col = colBase + j * 16 + l15;
#pragma unroll
                for (int q2 = 0; q2 < 4; q2++) {
                    int row = rowBase + i * 16 + kg * 4 + q2;
                    C1h[(size_t)row * N1 + col] = (f16)acc[i][j][q2];
                }
            }
        // fused attention logits: nblk covers half of one 256-col head
        const int head = nblk >> 1;
        const int cIn  = (nblk & 1) * 128 + wc * 64;
        float asv[4], adv[4];
#pragma unroll
        for (int j = 0; j < 4; j++) {
            asv[j] = a_s[head * 256 + cIn + j * 16 + l15];
            adv[j] = a_d[head * 256 + cIn + j * 16 + l15];
        }
#pragma unroll
        for (int i = 0; i < 4; i++)
#pragma unroll
            for (int q2 = 0; q2 < 4; q2++) {
                float vs = acc[i][0][q2] * asv[0] + acc[i][1][q2] * asv[1]
                         + acc[i][2][q2] * asv[2] + acc[i][3][q2] * asv[3];
                float vd = acc[i][0][q2] * adv[0] + acc[i][1][q2] * adv[1]
                         + acc[i][2][q2] * adv[2] + acc[i][3][q2] * adv[3];
                vs += __shfl_xor(vs, 1); vs += __shfl_xor(vs, 2);
                vs += __shfl_xor(vs, 4); vs += __shfl_xor(vs, 8);
                vd += __shfl_xor(vd, 1); vd += __shfl_xor(vd, 2);
                vd += __shfl_xor(vd, 4); vd += __shfl_xor(vd, 8);
                if (l15 == 0) {
                    int row = rowBase + i * 16 + kg * 4 + q2;
                    if (row < M) {
                        atomicAdd(&als[row * H + head], vs);
                        atomicAdd(&ald[row * H + head], vd);
                    }
                }
            }
    } else {
        const int cb2 = NB1 * 128;
#pragma unroll
        for (int i = 0; i < 4; i++)
#pragma unroll
            for (int j = 0; j < 4; j++) {
                int c2 = colBase + j * 16 + l15 - cb2;
                float bsum = bias1[c2] + bias2[c2];
#pragma unroll
                for (int q2 = 0; q2 < 4; q2++) {
                    int row = rowBase + i * 16 + kg * 4 + q2;
                    if (row < M) C2[(size_t)row * N2 + c2] = acc[i][j][q2] + bsum;
                }
            }
    }
}

// --------------------------- fused edge-softmax + aggregation (per node)
template <int H, bool MEAN>
__global__ __launch_bounds__(256) void smagg_k(const int* __restrict__ offs,
                                               const int* __restrict__ esrc,
                                               const float* __restrict__ als,
                                               const float* __restrict__ ald,
                                               const f16* __restrict__ hfeat16,
                                               float* __restrict__ out) {
    constexpr int NC = H * 256;
    __shared__ float s_l[128 * 9];
    __shared__ float s_p[128 * 9];
    __shared__ int   s_src[128];
    __shared__ float s_m[8], s_s[8], s_scale[8], s_ad[8];

    const int n = blockIdx.x;
    const int tid = threadIdx.x;
    const int base = offs[n], cnt = offs[n + 1] - base;

    if (tid < H) {
        s_m[tid] = -1e30f;
        s_s[tid] = 0.f;
        s_ad[tid] = ald[n * H + tid];
    }
    float acc[H];
#pragma unroll
    for (int h = 0; h < H; h++) acc[h] = 0.f;
    __syncthreads();

    for (int c0 = 0; c0 < cnt; c0 += 128) {
        const int mcnt = min(128, cnt - c0);
        if (tid < mcnt) {
            int src = esrc[base + c0 + tid];
            s_src[tid] = src;
#pragma unroll
            for (int h = 0; h < H; h++) {
                float l = als[src * H + h] + s_ad[h];
                l = (l < 0.f) ? 0.2f * l : l;
                s_l[tid * 9 + h] = l;
            }
        }
        __syncthreads();
        if (tid < H * 32) {
            int h = tid >> 5, l5 = tid & 31;
            float m = -1e30f;
            for (int e = l5; e < mcnt; e += 32) m = fmaxf(m, s_l[e * 9 + h]);
            for (int o = 16; o > 0; o >>= 1) m = fmaxf(m, __shfl_xor(m, o, 32));
            float mNew = fmaxf(s_m[h], m);
            float ssum = 0.f;
            for (int e = l5; e < mcnt; e += 32) ssum += __expf(s_l[e * 9 + h] - mNew);
            for (int o = 16; o > 0; o >>= 1) ssum += __shfl_xor(ssum, o, 32);
            if (l5 == 0) {
                float scale = __expf(s_m[h] - mNew);
                s_scale[h] = scale;
                s_s[h] = s_s[h] * scale + ssum;
                s_m[h] = mNew;
            }
        }
        __syncthreads();
        if (tid < mcnt) {
#pragma unroll
            for (int h = 0; h < H; h++)
                s_p[tid * 9 + h] = __expf(s_l[tid * 9 + h] - s_m[h]);
        }
#pragma unroll
        for (int h = 0; h < H; h++) acc[h] *= s_scale[h];
        __syncthreads();
        for (int e = 0; e < mcnt; e++) {
            const f16* hp = hfeat16 + (size_t)s_src[e] * NC + tid;
#pragma unroll
            for (int h = 0; h < H; h++)
                acc[h] += s_p[e * 9 + h] * (float)hp[h * 256];
        }
        __syncthreads();
    }

    if (MEAN) {
        float v = 0.f;
#pragma unroll
        for (int h = 0; h < H; h++) v += acc[h] / (s_s[h] + 1e-16f);
        out[(size_t)n * 256 + tid] += v * (1.f / 6.f);
    } else {
#pragma unroll
        for (int h = 0; h < H; h++)
            out[(size_t)n * NC + h * 256 + tid] += acc[h] / (s_s[h] + 1e-16f);
    }
}

// ------------------------------------------------------------------ driver
extern "C" void kernel_launch(void* const* d_in, const int* in_sizes, int n_in,
                              void* d_out, int out_size, void* d_ws, size_t ws_size,
                              hipStream_t stream) {
    const float* x   = (const float*)d_in[0];
    const int*   ei  = (const int*)d_in[1];
    const float* W1  = (const float*)d_in[2];
    const float* a1s = (const float*)d_in[3];
    const float* a1d = (const float*)d_in[4];
    const float* b1  = (const float*)d_in[5];
    const float* S1w = (const float*)d_in[6];
    const float* S1b = (const float*)d_in[7];
    const float* W2  = (const float*)d_in[8];
    const float* a2s = (const float*)d_in[9];
    const float* a2d = (const float*)d_in[10];
    const float* b2  = (const float*)d_in[11];
    const float* S2w = (const float*)d_in[12];
    const float* S2b = (const float*)d_in[13];
    const float* W3  = (const float*)d_in[14];
    const float* a3s = (const float*)d_in[15];
    const float* a3d = (const float*)d_in[16];
    const float* b3  = (const float*)d_in[17];
    const float* S3w = (const float*)d_in[18];
    const float* S3b = (const float*)d_in[19];
    float* out = (float*)d_out;

    float* ws = (float*)d_ws;
    size_t o = 0;
    float* bufA = ws + o; o += (size_t)NN * 1024;
    float* bufB = ws + o; o += (size_t)NN * 1024;
    float* als  = ws + o; o += (size_t)NN * 6;
    float* ald  = ws + o; o += (size_t)NN * 6;
    f16* hfeat16 = (f16*)(ws + o); o += (size_t)MPAD * 1536 / 2;
    f16* AhiT = (f16*)(ws + o); o += (size_t)MPAD * 1024 / 2;
    f16* AloT = (f16*)(ws + o); o += (size_t)MPAD * 1024 / 2;
    f16* Bt1  = (f16*)(ws + o); o += (size_t)16 * 4  * 4096 / 2;
    f16* Bt2  = (f16*)(ws + o); o += (size_t)16 * 32 * 4096 / 2;
    f16* Bt3  = (f16*)(ws + o); o += (size_t)14 * 32 * 4096 / 2;
    int* deg   = (int*)(ws + o);
    int* tmp   = deg + NN;
    int* bsum  = tmp + NN;
    int* bbase = bsum + 64;
    int* offs  = bbase + 64;
    int* pos   = offs + NN + 1;
    int* esrc  = pos + NN;

    // ---- CSR by dst (shared by all 3 layers)
    hipMemsetAsync(deg, 0, NN * sizeof(int), stream);
    count_deg_k<<<(ETOT + 255) / 256, 256, 0, stream>>>(ei, deg);
    sc1_k<<<40, 256, 0, stream>>>(deg, tmp, bsum);
    sc2_k<<<1, 64, 0, stream>>>(bsum, bbase);
    sc3_k<<<40, 256, 0, stream>>>(deg, tmp, bbase, offs, pos);
    scatter_k<<<(ETOT + 255) / 256, 256, 0, stream>>>(ei, pos, esrc);

    // ---- weight conversion (merged per-layer B = [W | S], hi only)
    convB_k<<<dim3(4, 16),  256, 0, stream>>>(W1,  Bt1, 1024, 0,    4);
    convB_k<<<dim3(4, 16),  256, 0, stream>>>(S1w, Bt1, 1024, 1024, 4);
    convB_k<<<dim3(4, 128), 256, 0, stream>>>(W2,  Bt2, 1024, 0,    32);
    convB_k<<<dim3(4, 128), 256, 0, stream>>>(S2w, Bt2, 1024, 1024, 32);
    convB_k<<<dim3(6, 128), 256, 0, stream>>>(W3,  Bt3, 1536, 0,    32);
    convB_k<<<dim3(1, 128), 256, 0, stream>>>(S3w, Bt3, 256,  1536, 32);

    // ---- Layer 1: A=x [N,128], N=2048 (8 blk feat | 8 blk skip)
    convA_k<false><<<MPAD * 16 / 256, 256, 0, stream>>>(x, AhiT, AloT, NN, 128, 4);
    hipMemsetAsync(als, 0, NN * 12 * sizeof(float), stream);
    mm_k<<<dim3(16, 79), 256, 0, stream>>>(AhiT, AloT, Bt1, bufA, hfeat16, S1b, b1,
                                           a1s, a1d, als, ald,
                                           NN, 4, 8, 1024, 1024, 4);
    smagg_k<4, false><<<NN, 256, 0, stream>>>(offs, esrc, als, ald, hfeat16, bufA);

    // ---- Layer 2
    convA_k<true><<<MPAD * 128 / 256, 256, 0, stream>>>(bufA, AhiT, AloT, NN, 1024, 7);
    hipMemsetAsync(als, 0, NN * 12 * sizeof(float), stream);
    mm_k<<<dim3(16, 79), 256, 0, stream>>>(AhiT, AloT, Bt2, bufB, hfeat16, S2b, b2,
                                           a2s, a2d, als, ald,
                                           NN, 32, 8, 1024, 1024, 4);
    smagg_k<4, false><<<NN, 256, 0, stream>>>(offs, esrc, als, ald, hfeat16, bufB);

    // ---- Layer 3: N=1792 (12 blk feat | 2 blk skip->out), mean over 6 heads
    convA_k<true><<<MPAD * 128 / 256, 256, 0, stream>>>(bufB, AhiT, AloT, NN, 1024, 7);
    hipMemsetAsync(als, 0, NN * 12 * sizeof(float), stream);
    mm_k<<<dim3(14, 79), 256, 0, stream>>>(AhiT, AloT, Bt3, out, hfeat16, S3b, b3,
                                           a3s, a3d, als, ald,
                                           NN, 32, 12, 1536, 256, 6);
    smagg_k<6, true><<<NN, 256, 0, stream>>>(offs, esrc, als, ald, hfeat16, out);
}

// Round 6
// 553.553 us; speedup vs baseline: 3.3212x; 1.1675x over previous
//
#include <hip/hip_runtime.h>
#include <cfloat>
#include <cmath>
#include <cstdint>

#define NN 10000
#define EE 160000
#define ETOT 170000   // EE + NN self loops
#define MPAD 10112    // 79*128

typedef _Float16 f16;
typedef __attribute__((ext_vector_type(8))) _Float16 f16x8;
typedef __attribute__((ext_vector_type(4))) float f32x4;

// ---------------------------------------------------------------- CSR build
__global__ __launch_bounds__(256) void count_deg_k(const int* __restrict__ ei,
                                                   int* __restrict__ deg) {
    int e = blockIdx.x * 256 + threadIdx.x;
    if (e < ETOT) {
        int dst = (e < EE) ? ei[EE + e] : (e - EE);
        atomicAdd(&deg[dst], 1);
    }
}

__global__ __launch_bounds__(256) void sc1_k(const int* __restrict__ deg,
                                             int* __restrict__ tmp,
                                             int* __restrict__ bsum) {
    __shared__ int s[256];
    int i = blockIdx.x * 256 + threadIdx.x;
    int v = (i < NN) ? deg[i] : 0;
    s[threadIdx.x] = v;
    __syncthreads();
    for (int d = 1; d < 256; d <<= 1) {
        int t = (threadIdx.x >= d) ? s[threadIdx.x - d] : 0;
        __syncthreads();
        s[threadIdx.x] += t;
        __syncthreads();
    }
    if (i < NN) tmp[i] = s[threadIdx.x];
    if (threadIdx.x == 255) bsum[blockIdx.x] = s[255];
}

__global__ __launch_bounds__(64) void sc2_k(const int* __restrict__ bsum,
                                            int* __restrict__ bbase) {
    int lane = threadIdx.x;
    int v = (lane < 40) ? bsum[lane] : 0;
    int incl = v;
    for (int d = 1; d < 64; d <<= 1) {
        int t = __shfl_up(incl, d, 64);
        if (lane >= d) incl += t;
    }
    if (lane < 40) bbase[lane] = incl - v;
}

__global__ __launch_bounds__(256) void sc3_k(const int* __restrict__ deg,
                                             const int* __restrict__ tmp,
                                             const int* __restrict__ bbase,
                                             int* __restrict__ offs,
                                             int* __restrict__ pos) {
    int i = blockIdx.x * 256 + threadIdx.x;
    if (i < NN) {
        int incl = tmp[i] + bbase[blockIdx.x];
        offs[i + 1] = incl;
        pos[i]      = incl - deg[i];
    }
    if (i == 0) offs[0] = 0;
}

__global__ __launch_bounds__(256) void scatter_k(const int* __restrict__ ei,
                                                 int* __restrict__ pos,
                                                 int* __restrict__ esrc) {
    int e = blockIdx.x * 256 + threadIdx.x;
    if (e < ETOT) {
        int dst = (e < EE) ? ei[EE + e] : (e - EE);
        int src = (e < EE) ? ei[e]      : (e - EE);
        int p = atomicAdd(&pos[dst], 1);
        esrc[p] = src;
    }
}

// --------------------------------------------- fp32 -> tiled f16 hi/lo
// Tile = 128 rows x 32 k (8KB). Row r at r*64B; 16B chunk ko at ko^((r>>1)&3).
__device__ __forceinline__ int swz(int r, int ko) { return ko ^ ((r >> 1) & 3); }

template <bool DOELU>
__global__ __launch_bounds__(256) void convA_k(const float* __restrict__ A,
                                               f16* __restrict__ hi,
                                               f16* __restrict__ lo,
                                               int M, int K, int kshift) {
    int idx = blockIdx.x * 256 + threadIdx.x;
    int row = idx >> kshift;
    int kc  = idx & ((1 << kshift) - 1);
    float v[8];
    if (row < M) {
        const float* p = A + (size_t)row * K + kc * 8;
        float4 f0 = *(const float4*)p, f1 = *(const float4*)(p + 4);
        v[0]=f0.x; v[1]=f0.y; v[2]=f0.z; v[3]=f0.w;
        v[4]=f1.x; v[5]=f1.y; v[6]=f1.z; v[7]=f1.w;
        if (DOELU) {
#pragma unroll
            for (int i = 0; i < 8; i++) v[i] = (v[i] > 0.f) ? v[i] : expf(v[i]) - 1.f;
        }
    } else {
#pragma unroll
        for (int i = 0; i < 8; i++) v[i] = 0.f;
    }
    int mblk = row >> 7, r = row & 127;
    int kblk = kc >> 2,  ko = kc & 3;
    int KB = K >> 5;
    size_t off = ((size_t)(mblk * KB + kblk)) * 4096 + r * 32 + swz(r, ko) * 8;
    f16x8 h, l;
#pragma unroll
    for (int i = 0; i < 8; i++) {
        f16 hv = (f16)v[i];
        h[i] = hv;
        l[i] = (f16)(v[i] - (float)hv);
    }
    *(f16x8*)(hi + off) = h;
    *(f16x8*)(lo + off) = l;
}

// B [K,NcSrc] fp32 -> transposed tiled f16 (hi only)
__global__ __launch_bounds__(256) void convB_k(const float* __restrict__ B,
                                               f16* __restrict__ Bdst,
                                               int NcSrc, int colOff, int KB) {
    int n  = blockIdx.x * 256 + threadIdx.x;
    int kc = blockIdx.y;
    const float* p = B + (size_t)(kc * 8) * NcSrc + n;
    int gcol = colOff + n;
    int nblk = gcol >> 7, r = gcol & 127;
    int kblk = kc >> 2,  ko = kc & 3;
    size_t off = ((size_t)(nblk * KB + kblk)) * 4096 + r * 32 + swz(r, ko) * 8;
    f16x8 h;
#pragma unroll
    for (int i = 0; i < 8; i++) h[i] = (f16)p[(size_t)i * NcSrc];
    *(f16x8*)(Bdst + off) = h;
}

// ---------------------------------------------------------- f16 MFMA GEMM
// C = (Ahi+Alo)*Bhi. 128x128 tile, BK=32, 4 waves (2x2), wave = 64x64.
// 2-phase pipeline: double-buffered LDS, stage(next) issued BEFORE compute,
// single __syncthreads per K-step (vmcnt drain lands after compute).
__device__ __forceinline__ void gl_lds16(const void* g, void* l) {
    __builtin_amdgcn_global_load_lds(
        (const __attribute__((address_space(1))) uint32_t*)g,
        (__attribute__((address_space(3))) uint32_t*)l, 16, 0, 0);
}

#define MMBUF 24576

__global__ __launch_bounds__(256) void mm_k(const f16* __restrict__ Ahi,
                                            const f16* __restrict__ Alo,
                                            const f16* __restrict__ Bhi,
                                            float* __restrict__ C2,
                                            f16* __restrict__ C1h,
                                            const float* __restrict__ bias1,
                                            const float* __restrict__ bias2,
                                            const float* __restrict__ a_s,
                                            const float* __restrict__ a_d,
                                            float* __restrict__ als,
                                            float* __restrict__ ald,
                                            int M, int KB, int NB1,
                                            int N1, int N2, int H) {
    __shared__ __align__(16) char lds[2 * MMBUF];  // per buf: Ahi|Alo|Bhi 8KB each
    const int tid = threadIdx.x;

    // bijective XCD chunking: consecutive remapped ids share mblk on one XCD
    const int nwg  = gridDim.x * gridDim.y;
    const int orig = blockIdx.y * gridDim.x + blockIdx.x;
    const int q = nwg >> 3, rr = nwg & 7;
    const int xcd = orig & 7, rk = orig >> 3;
    const int lin = (xcd < rr ? xcd * (q + 1) : rr * (q + 1) + (xcd - rr) * q) + rk;
    const int mblk = lin / gridDim.x, nblk = lin % gridDim.x;

    const int lane = tid & 63, w = tid >> 6;
    const int wr = w >> 1, wc = w & 1;
    const int kg = lane >> 4, l15 = lane & 15;

    int offA[4], offB[4];
#pragma unroll
    for (int t = 0; t < 4; t++) {
        int ra = wr * 64 + t * 16 + l15;
        offA[t] = ra * 64 + swz(ra, kg) * 16;
        int rb = wc * 64 + t * 16 + l15;
        offB[t] = 16384 + rb * 64 + swz(rb, kg) * 16;
    }

    const char* gAh = (const char*)Ahi + (size_t)mblk * KB * 8192;
    const char* gAl = (const char*)Alo + (size_t)mblk * KB * 8192;
    const char* gBh = (const char*)Bhi + (size_t)nblk * KB * 8192;

    f32x4 acc[4][4];
#pragma unroll
    for (int i = 0; i < 4; i++)
#pragma unroll
        for (int j = 0; j < 4; j++) acc[i][j] = (f32x4){0.f, 0.f, 0.f, 0.f};

    const int t16 = tid * 16;
    auto stage = [&](int kb, int buf) {
        const size_t tk = (size_t)kb * 8192;
        char* l = lds + buf * MMBUF;
        gl_lds16(gAh + tk + t16,        l + t16);
        gl_lds16(gAh + tk + 4096 + t16, l + 4096 + t16);
        gl_lds16(gAl + tk + t16,        l + 8192 + t16);
        gl_lds16(gAl + tk + 4096 + t16, l + 12288 + t16);
        gl_lds16(gBh + tk + t16,        l + 16384 + t16);
        gl_lds16(gBh + tk + 4096 + t16, l + 20480 + t16);
    };

    stage(0, 0);
    __syncthreads();   // vmcnt(0)+lgkmcnt(0)+barrier

    for (int kb = 0; kb < KB; kb++) {
        const int cur = kb & 1;
        if (kb + 1 < KB) stage(kb + 1, cur ^ 1);   // in flight across compute

        const char* l = lds + cur * MMBUF;
        f16x8 ah[4], al[4], b[4];
#pragma unroll
        for (int t = 0; t < 4; t++) {
            ah[t] = *(const f16x8*)(l + offA[t]);
            al[t] = *(const f16x8*)(l + 8192 + offA[t]);
            b[t]  = *(const f16x8*)(l + offB[t]);
        }
#pragma unroll
        for (int i = 0; i < 4; i++)
#pragma unroll
            for (int j = 0; j < 4; j++) {
                acc[i][j] = __builtin_amdgcn_mfma_f32_16x16x32_f16(ah[i], b[j], acc[i][j], 0, 0, 0);
                acc[i][j] = __builtin_amdgcn_mfma_f32_16x16x32_f16(al[i], b[j], acc[i][j], 0, 0, 0);
            }
        __syncthreads();   // drains next-tile loads (latency covered by MFMA)
    }

    const int rowBase = mblk * 128 + wr * 64;
    const int colBase = nblk * 128 + wc * 64;
    if (nblk < NB1) {
        // f16 feature write (garbage pad rows never read downstream)
#pragma unroll
        for (int i = 0; i < 4; i++)
#pragma unroll
            for (int j = 0; j < 4; j++) {
                int col = colBase + j * 16 + l15;
#pragma unroll
                for (int q2 = 0; q2 < 4; q2++) {
                    int row = rowBase + i * 16 + kg * 4 + q2;
                    C1h[(size_t)row * N1 + col] = (f16)acc[i][j][q2];
                }
            }
        // fused attention logits: nblk covers half of one 256-col head
        const int head = nblk >> 1;
        const int cIn  = (nblk & 1) * 128 + wc * 64;
        float asv[4], adv[4];
#pragma unroll
        for (int j = 0; j < 4; j++) {
            asv[j] = a_s[head * 256 + cIn + j * 16 + l15];
            adv[j] = a_d[head * 256 + cIn + j * 16 + l15];
        }
#pragma unroll
        for (int i = 0; i < 4; i++)
#pragma unroll
            for (int q2 = 0; q2 < 4; q2++) {
                float vs = acc[i][0][q2] * asv[0] + acc[i][1][q2] * asv[1]
                         + acc[i][2][q2] * asv[2] + acc[i][3][q2] * asv[3];
                float vd = acc[i][0][q2] * adv[0] + acc[i][1][q2] * adv[1]
                         + acc[i][2][q2] * adv[2] + acc[i][3][q2] * adv[3];
                vs += __shfl_xor(vs, 1); vs += __shfl_xor(vs, 2);
                vs += __shfl_xor(vs, 4); vs += __shfl_xor(vs, 8);
                vd += __shfl_xor(vd, 1); vd += __shfl_xor(vd, 2);
                vd += __shfl_xor(vd, 4); vd += __shfl_xor(vd, 8);
                if (l15 == 0) {
                    int row = rowBase + i * 16 + kg * 4 + q2;
                    if (row < M) {
                        atomicAdd(&als[row * H + head], vs);
                        atomicAdd(&ald[row * H + head], vd);
                    }
                }
            }
    } else {
        const int cb2 = NB1 * 128;
#pragma unroll
        for (int i = 0; i < 4; i++)
#pragma unroll
            for (int j = 0; j < 4; j++) {
                int c2 = colBase + j * 16 + l15 - cb2;
                float bsum = bias1[c2] + bias2[c2];
#pragma unroll
                for (int q2 = 0; q2 < 4; q2++) {
                    int row = rowBase + i * 16 + kg * 4 + q2;
                    if (row < M) C2[(size_t)row * N2 + c2] = acc[i][j][q2] + bsum;
                }
            }
    }
}

// --------------------------- fused edge-softmax + aggregation (per node)
// MEAN=false (concat layers): epilogue = skip + agg -> ELU -> next layer's
// tiled hi/lo A (K_next = 1024, KB = 32). MEAN=true: final out += mean.
template <int H, bool MEAN>
__global__ __launch_bounds__(256) void smagg_k(const int* __restrict__ offs,
                                               const int* __restrict__ esrc,
                                               const float* __restrict__ als,
                                               const float* __restrict__ ald,
                                               const f16* __restrict__ hfeat16,
                                               const float* __restrict__ skipin,
                                               float* __restrict__ outf,
                                               f16* __restrict__ hiT,
                                               f16* __restrict__ loT) {
    constexpr int NC = H * 256;
    __shared__ float s_l[128 * 9];
    __shared__ float s_p[128 * 9];
    __shared__ int   s_src[128];
    __shared__ float s_m[8], s_s[8], s_scale[8], s_ad[8];

    const int n = blockIdx.x;
    const int tid = threadIdx.x;
    const int base = offs[n], cnt = offs[n + 1] - base;

    if (tid < H) {
        s_m[tid] = -1e30f;
        s_s[tid] = 0.f;
        s_ad[tid] = ald[n * H + tid];
    }
    float acc[H];
#pragma unroll
    for (int h = 0; h < H; h++) acc[h] = 0.f;
    __syncthreads();

    for (int c0 = 0; c0 < cnt; c0 += 128) {
        const int mcnt = min(128, cnt - c0);
        if (tid < mcnt) {
            int src = esrc[base + c0 + tid];
            s_src[tid] = src;
#pragma unroll
            for (int h = 0; h < H; h++) {
                float l = als[src * H + h] + s_ad[h];
                l = (l < 0.f) ? 0.2f * l : l;
                s_l[tid * 9 + h] = l;
            }
        }
        __syncthreads();
        if (tid < H * 32) {
            int h = tid >> 5, l5 = tid & 31;
            float m = -1e30f;
            for (int e = l5; e < mcnt; e += 32) m = fmaxf(m, s_l[e * 9 + h]);
            for (int o = 16; o > 0; o >>= 1) m = fmaxf(m, __shfl_xor(m, o, 32));
            float mNew = fmaxf(s_m[h], m);
            float ssum = 0.f;
            for (int e = l5; e < mcnt; e += 32) ssum += __expf(s_l[e * 9 + h] - mNew);
            for (int o = 16; o > 0; o >>= 1) ssum += __shfl_xor(ssum, o, 32);
            if (l5 == 0) {
                float scale = __expf(s_m[h] - mNew);
                s_scale[h] = scale;
                s_s[h] = s_s[h] * scale + ssum;
                s_m[h] = mNew;
            }
        }
        __syncthreads();
        if (tid < mcnt) {
#pragma unroll
            for (int h = 0; h < H; h++)
                s_p[tid * 9 + h] = __expf(s_l[tid * 9 + h] - s_m[h]);
        }
#pragma unroll
        for (int h = 0; h < H; h++) acc[h] *= s_scale[h];
        __syncthreads();
        for (int e = 0; e < mcnt; e++) {
            const f16* hp = hfeat16 + (size_t)s_src[e] * NC + tid;
#pragma unroll
            for (int h = 0; h < H; h++)
                acc[h] += s_p[e * 9 + h] * (float)hp[h * 256];
        }
        __syncthreads();
    }

    if (MEAN) {
        float v = 0.f;
#pragma unroll
        for (int h = 0; h < H; h++) v += acc[h] / (s_s[h] + 1e-16f);
        outf[(size_t)n * 256 + tid] += v * (1.f / 6.f);
    } else {
        const int mblk = n >> 7, r = n & 127;
#pragma unroll
        for (int h = 0; h < H; h++) {
            int c = h * 256 + tid;
            float v = skipin[(size_t)n * NC + c] + acc[h] / (s_s[h] + 1e-16f);
            v = (v > 0.f) ? v : expf(v) - 1.f;          // ELU
            f16 hv = (f16)v;
            f16 lv = (f16)(v - (float)hv);
            int kblk = c >> 5, ko = (c >> 3) & 3;
            size_t off = ((size_t)(mblk * 32 + kblk)) * 4096
                       + r * 32 + swz(r, ko) * 8 + (c & 7);
            hiT[off] = hv;
            loT[off] = lv;
        }
    }
}

// ------------------------------------------------------------------ driver
extern "C" void kernel_launch(void* const* d_in, const int* in_sizes, int n_in,
                              void* d_out, int out_size, void* d_ws, size_t ws_size,
                              hipStream_t stream) {
    const float* x   = (const float*)d_in[0];
    const int*   ei  = (const int*)d_in[1];
    const float* W1  = (const float*)d_in[2];
    const float* a1s = (const float*)d_in[3];
    const float* a1d = (const float*)d_in[4];
    const float* b1  = (const float*)d_in[5];
    const float* S1w = (const float*)d_in[6];
    const float* S1b = (const float*)d_in[7];
    const float* W2  = (const float*)d_in[8];
    const float* a2s = (const float*)d_in[9];
    const float* a2d = (const float*)d_in[10];
    const float* b2  = (const float*)d_in[11];
    const float* S2w = (const float*)d_in[12];
    const float* S2b = (const float*)d_in[13];
    const float* W3  = (const float*)d_in[14];
    const float* a3s = (const float*)d_in[15];
    const float* a3d = (const float*)d_in[16];
    const float* b3  = (const float*)d_in[17];
    const float* S3w = (const float*)d_in[18];
    const float* S3b = (const float*)d_in[19];
    float* out = (float*)d_out;

    float* ws = (float*)d_ws;
    size_t o = 0;
    float* bufA = ws + o; o += (size_t)NN * 1024;   // skip outputs (C2)
    float* bufB = ws + o; o += (size_t)NN * 1024;
    float* als  = ws + o; o += (size_t)NN * 6;
    float* ald  = ws + o; o += (size_t)NN * 6;
    f16* hfeat16 = (f16*)(ws + o); o += (size_t)MPAD * 1536 / 2;
    f16* AhiT = (f16*)(ws + o); o += (size_t)MPAD * 1024 / 2;
    f16* AloT = (f16*)(ws + o); o += (size_t)MPAD * 1024 / 2;
    f16* Bt1  = (f16*)(ws + o); o += (size_t)16 * 4  * 4096 / 2;
    f16* Bt2  = (f16*)(ws + o); o += (size_t)16 * 32 * 4096 / 2;
    f16* Bt3  = (f16*)(ws + o); o += (size_t)14 * 32 * 4096 / 2;
    int* deg   = (int*)(ws + o);
    int* tmp   = deg + NN;
    int* bsum  = tmp + NN;
    int* bbase = bsum + 64;
    int* offs  = bbase + 64;
    int* pos   = offs + NN + 1;
    int* esrc  = pos + NN;

    // ---- CSR by dst (shared by all 3 layers)
    hipMemsetAsync(deg, 0, NN * sizeof(int), stream);
    count_deg_k<<<(ETOT + 255) / 256, 256, 0, stream>>>(ei, deg);
    sc1_k<<<40, 256, 0, stream>>>(deg, tmp, bsum);
    sc2_k<<<1, 64, 0, stream>>>(bsum, bbase);
    sc3_k<<<40, 256, 0, stream>>>(deg, tmp, bbase, offs, pos);
    scatter_k<<<(ETOT + 255) / 256, 256, 0, stream>>>(ei, pos, esrc);

    // ---- weight conversion (merged per-layer B = [W | S], hi only)
    convB_k<<<dim3(4, 16),  256, 0, stream>>>(W1,  Bt1, 1024, 0,    4);
    convB_k<<<dim3(4, 16),  256, 0, stream>>>(S1w, Bt1, 1024, 1024, 4);
    convB_k<<<dim3(4, 128), 256, 0, stream>>>(W2,  Bt2, 1024, 0,    32);
    convB_k<<<dim3(4, 128), 256, 0, stream>>>(S2w, Bt2, 1024, 1024, 32);
    convB_k<<<dim3(6, 128), 256, 0, stream>>>(W3,  Bt3, 1536, 0,    32);
    convB_k<<<dim3(1, 128), 256, 0, stream>>>(S3w, Bt3, 256,  1536, 32);

    // ---- Layer 1: A=x [N,128], N=2048 (8 blk feat | 8 blk skip)
    convA_k<false><<<MPAD * 16 / 256, 256, 0, stream>>>(x, AhiT, AloT, NN, 128, 4);
    hipMemsetAsync(als, 0, NN * 12 * sizeof(float), stream);
    mm_k<<<dim3(16, 79), 256, 0, stream>>>(AhiT, AloT, Bt1, bufA, hfeat16, S1b, b1,
                                           a1s, a1d, als, ald,
                                           NN, 4, 8, 1024, 1024, 4);
    // smagg writes layer-2's tiled A (ELU fused), consuming skip from bufA
    smagg_k<4, false><<<NN, 256, 0, stream>>>(offs, esrc, als, ald, hfeat16,
                                              bufA, nullptr, AhiT, AloT);

    // ---- Layer 2
    hipMemsetAsync(als, 0, NN * 12 * sizeof(float), stream);
    mm_k<<<dim3(16, 79), 256, 0, stream>>>(AhiT, AloT, Bt2, bufB, hfeat16, S2b, b2,
                                           a2s, a2d, als, ald,
                                           NN, 32, 8, 1024, 1024, 4);
    smagg_k<4, false><<<NN, 256, 0, stream>>>(offs, esrc, als, ald, hfeat16,
                                              bufB, nullptr, AhiT, AloT);

    // ---- Layer 3: N=1792 (12 blk feat | 2 blk skip->out), mean over 6 heads
    hipMemsetAsync(als, 0, NN * 12 * sizeof(float), stream);
    mm_k<<<dim3(14, 79), 256, 0, stream>>>(AhiT, AloT, Bt3, out, hfeat16, S3b, b3,
                                           a3s, a3d, als, ald,
                                           NN, 32, 12, 1536, 256, 6);
    smagg_k<6, true><<<NN, 256, 0, stream>>>(offs, esrc, als, ald, hfeat16,
                                             nullptr, out, nullptr, nullptr);
}